// Round 1
// baseline (2902.226 us; speedup 1.0000x reference)
//
#include <hip/hip_runtime.h>
#include <hip/hip_bf16.h>

#define DIM 128

__device__ __forceinline__ float elu_f(float x) { return x > 0.f ? x : expm1f(x); }

// h = elu?(x) @ W ; s_src[n] = h[n]·a_src ; s_dst[n] = h[n]·a_dst
template<int APPLY_ELU>
__global__ __launch_bounds__(256) void gemm_s(const float* __restrict__ x, const float* __restrict__ W,
                                              const float* __restrict__ a_src, const float* __restrict__ a_dst,
                                              float* __restrict__ h, float* __restrict__ s_src,
                                              float* __restrict__ s_dst, int N)
{
    __shared__ float Ws[DIM * DIM];     // 64 KB
    __shared__ float xs[2][DIM];
    __shared__ float red[2][2][2];      // [row][src/dst][wave]
    for (int i = threadIdx.x; i < DIM * DIM; i += 256) Ws[i] = W[i];
    const int r = threadIdx.x >> 7;     // row slot 0/1
    const int j = threadIdx.x & 127;    // output column
    const float asj = a_src[j];
    const float adj = a_dst[j];
    __syncthreads();
    for (int base = blockIdx.x * 2; base < N; base += gridDim.x * 2) {
        const int n = base + r;
        const bool active = n < N;
        float xv = 0.f;
        if (active) {
            xv = x[(size_t)n * DIM + j];
            if (APPLY_ELU) xv = elu_f(xv);
        }
        xs[r][j] = xv;
        __syncthreads();
        float acc = 0.f;
#pragma unroll 16
        for (int k = 0; k < DIM; ++k) acc = fmaf(xs[r][k], Ws[k * DIM + j], acc);
        if (active) h[(size_t)n * DIM + j] = acc;
        float v1 = acc * asj, v2 = acc * adj;
#pragma unroll
        for (int o = 32; o > 0; o >>= 1) { v1 += __shfl_down(v1, o); v2 += __shfl_down(v2, o); }
        if ((threadIdx.x & 63) == 0) {
            const int w = (threadIdx.x >> 6) & 1;   // wave within row
            red[r][0][w] = v1;
            red[r][1][w] = v2;
        }
        __syncthreads();
        if (active && j == 0) {
            s_src[n] = red[r][0][0] + red[r][0][1];
            s_dst[n] = red[r][1][0] + red[r][1][1];
        }
        __syncthreads();
    }
}

// logits[e] = leaky_relu(s_src[src]+s_dst[dst]); atomicMax(m_enc[dst], enc(logit))
__global__ __launch_bounds__(256) void edge_logits(const int* __restrict__ src, const int* __restrict__ dst,
                                                   const float* __restrict__ s_src, const float* __restrict__ s_dst,
                                                   float* __restrict__ logits, unsigned* __restrict__ m_enc, int E)
{
    int e = blockIdx.x * blockDim.x + threadIdx.x;
    if (e >= E) return;
    float l = s_src[src[e]] + s_dst[dst[e]];
    l = l >= 0.f ? l : 0.2f * l;        // leaky_relu slope 0.2
    logits[e] = l;
    unsigned u = __float_as_uint(l);
    unsigned enc = (u & 0x80000000u) ? ~u : (u | 0x80000000u);  // order-preserving
    atomicMax(&m_enc[dst[e]], enc);
}

// ev_out[e] = exp(l - m[dst]) * edge_value; denom[dst] += ev_out  (in-place over logits buffer)
__global__ __launch_bounds__(256) void edge_exp(const int* __restrict__ dst, const float* __restrict__ ev,
                                                const unsigned* __restrict__ m_enc,
                                                float* __restrict__ logits, float* __restrict__ denom, int E)
{
    int e = blockIdx.x * blockDim.x + threadIdx.x;
    if (e >= E) return;
    unsigned enc = m_enc[dst[e]];
    unsigned u = (enc & 0x80000000u) ? (enc ^ 0x80000000u) : ~enc;
    float m = __uint_as_float(u);
    float x = expf(logits[e] - m) * ev[e];
    logits[e] = x;
    atomicAdd(&denom[dst[e]], x);
}

// out[dst] += h[src] * (e / (denom[dst]+1e-16));  32 lanes per edge, 4 floats each
__global__ __launch_bounds__(256) void edge_scatter(const int* __restrict__ src, const int* __restrict__ dst,
                                                    const float* __restrict__ ev, const float* __restrict__ denom,
                                                    const float* __restrict__ h, float* __restrict__ out, int E)
{
    long long t = (long long)blockIdx.x * blockDim.x + threadIdx.x;
    int e = (int)(t >> 5);
    if (e >= E) return;
    int j = ((int)t & 31) * 4;
    int d = dst[e];
    float c = ev[e] / (denom[d] + 1e-16f);
    const float4 hv = *reinterpret_cast<const float4*>(&h[(size_t)src[e] * DIM + j]);
    float* o = &out[(size_t)d * DIM + j];
    atomicAdd(o + 0, hv.x * c);
    atomicAdd(o + 1, hv.y * c);
    atomicAdd(o + 2, hv.z * c);
    atomicAdd(o + 3, hv.w * c);
}

// out = [elu(u[user_id]) ; elu(it[item_id])]
__global__ __launch_bounds__(256) void gather_out(const int* __restrict__ uid, const int* __restrict__ iid,
                                                  const float* __restrict__ u, const float* __restrict__ it,
                                                  float* __restrict__ out, int B)
{
    int t = blockIdx.x * blockDim.x + threadIdx.x;
    int total = B * DIM;
    if (t < total) {
        int b = t >> 7, j = t & 127;
        out[t] = elu_f(u[(size_t)uid[b] * DIM + j]);
    } else if (t < 2 * total) {
        int tt = t - total;
        int b = tt >> 7, j = tt & 127;
        out[t] = elu_f(it[(size_t)iid[b] * DIM + j]);
    }
}

extern "C" void kernel_launch(void* const* d_in, const int* in_sizes, int n_in,
                              void* d_out, int out_size, void* d_ws, size_t ws_size,
                              hipStream_t stream)
{
    const int*   uedg    = (const int*)d_in[0];
    const int*   iedg    = (const int*)d_in[1];
    const int*   user_id = (const int*)d_in[2];
    const int*   item_id = (const int*)d_in[3];
    const float* uval    = (const float*)d_in[4];
    const float* ival    = (const float*)d_in[5];
    const float* umat    = (const float*)d_in[6];
    const float* imat    = (const float*)d_in[7];
    const float* W_u1 = (const float*)d_in[8];
    const float* as_u1 = (const float*)d_in[9];
    const float* ad_u1 = (const float*)d_in[10];
    const float* W_u2 = (const float*)d_in[11];
    const float* as_u2 = (const float*)d_in[12];
    const float* ad_u2 = (const float*)d_in[13];
    const float* W_i1 = (const float*)d_in[14];
    const float* as_i1 = (const float*)d_in[15];
    const float* ad_i1 = (const float*)d_in[16];
    const float* W_i2 = (const float*)d_in[17];
    const float* as_i2 = (const float*)d_in[18];
    const float* ad_i2 = (const float*)d_in[19];

    const int EU = in_sizes[0] / 2;     // 400000
    const int EI = in_sizes[1] / 2;     // 200000
    const int B  = in_sizes[2];         // 4096
    const int NU = in_sizes[6] / DIM;   // 100000
    const int NI = in_sizes[7] / DIM;   // 50000

    float* h     = (float*)d_ws;                        // NU*DIM
    float* xb_u  = h     + (size_t)NU * DIM;            // NU*DIM
    float* xb_i  = xb_u  + (size_t)NU * DIM;            // NI*DIM
    float* ssrc  = xb_i  + (size_t)NI * DIM;            // NU
    float* sdst  = ssrc  + NU;                          // NU
    unsigned* menc = (unsigned*)(sdst + NU);            // NU
    float* denom = (float*)(menc + NU);                 // NU
    float* etmp  = denom + NU;                          // EU

    auto layer = [&](const float* x, const int* ei, const float* evv,
                     const float* W, const float* as, const float* ad,
                     float* outb, int N, int E, bool applyElu) {
        const int* srcp = ei;
        const int* dstp = ei + E;
        if (applyElu)
            gemm_s<1><<<512, 256, 0, stream>>>(x, W, as, ad, h, ssrc, sdst, N);
        else
            gemm_s<0><<<512, 256, 0, stream>>>(x, W, as, ad, h, ssrc, sdst, N);
        hipMemsetAsync(menc, 0, (size_t)N * 4, stream);
        edge_logits<<<(E + 255) / 256, 256, 0, stream>>>(srcp, dstp, ssrc, sdst, etmp, menc, E);
        hipMemsetAsync(denom, 0, (size_t)N * 4, stream);
        edge_exp<<<(E + 255) / 256, 256, 0, stream>>>(dstp, evv, menc, etmp, denom, E);
        hipMemsetAsync(outb, 0, (size_t)N * DIM * 4, stream);
        long long thr = (long long)E * 32;
        edge_scatter<<<(int)((thr + 255) / 256), 256, 0, stream>>>(srcp, dstp, etmp, denom, h, outb, E);
    };

    // Layer order mirrors the reference: i1, u1, i2, u2
    layer(imat, iedg, ival, W_i1, as_i1, ad_i1, xb_i, NI, EI, false);
    layer(umat, uedg, uval, W_u1, as_u1, ad_u1, xb_u, NU, EU, false);
    layer(xb_i, iedg, ival, W_i2, as_i2, ad_i2, xb_i, NI, EI, true);   // in==out OK: x fully consumed by gemm before memset
    layer(xb_u, uedg, uval, W_u2, as_u2, ad_u2, xb_u, NU, EU, true);

    int total = 2 * B * DIM;
    gather_out<<<(total + 255) / 256, 256, 0, stream>>>(user_id, item_id, xb_u, xb_i, (float*)d_out, B);
}

// Round 2
// 924.807 us; speedup vs baseline: 3.1382x; 3.1382x over previous
//
#include <hip/hip_runtime.h>
#include <hip/hip_bf16.h>

#define DIM 128

__device__ __forceinline__ float elu_f(float x) { return x > 0.f ? x : expm1f(x); }

// h = elu?(x) @ W ; s_src[n] = h[n]·a_src ; s_dst[n] = h[n]·a_dst
template<int APPLY_ELU>
__global__ __launch_bounds__(256) void gemm_s(const float* __restrict__ x, const float* __restrict__ W,
                                              const float* __restrict__ a_src, const float* __restrict__ a_dst,
                                              float* __restrict__ h, float* __restrict__ s_src,
                                              float* __restrict__ s_dst, int N)
{
    __shared__ float Ws[DIM * DIM];     // 64 KB
    __shared__ float xs[2][DIM];
    __shared__ float red[2][2][2];      // [row][src/dst][wave]
    for (int i = threadIdx.x; i < DIM * DIM; i += 256) Ws[i] = W[i];
    const int r = threadIdx.x >> 7;     // row slot 0/1
    const int j = threadIdx.x & 127;    // output column
    const float asj = a_src[j];
    const float adj = a_dst[j];
    __syncthreads();
    for (int base = blockIdx.x * 2; base < N; base += gridDim.x * 2) {
        const int n = base + r;
        const bool active = n < N;
        float xv = 0.f;
        if (active) {
            xv = x[(size_t)n * DIM + j];
            if (APPLY_ELU) xv = elu_f(xv);
        }
        xs[r][j] = xv;
        __syncthreads();
        float acc = 0.f;
#pragma unroll 16
        for (int k = 0; k < DIM; ++k) acc = fmaf(xs[r][k], Ws[k * DIM + j], acc);
        if (active) h[(size_t)n * DIM + j] = acc;
        float v1 = acc * asj, v2 = acc * adj;
#pragma unroll
        for (int o = 32; o > 0; o >>= 1) { v1 += __shfl_down(v1, o); v2 += __shfl_down(v2, o); }
        if ((threadIdx.x & 63) == 0) {
            const int w = (threadIdx.x >> 6) & 1;   // wave within row
            red[r][0][w] = v1;
            red[r][1][w] = v2;
        }
        __syncthreads();
        if (active && j == 0) {
            s_src[n] = red[r][0][0] + red[r][0][1];
            s_dst[n] = red[r][1][0] + red[r][1][1];
        }
        __syncthreads();
    }
}

// ---------------- CSR build (once per graph per launch) ----------------

__global__ __launch_bounds__(256) void hist_kernel(const int* __restrict__ dst, int E, int* __restrict__ cnt)
{
    int e = blockIdx.x * blockDim.x + threadIdx.x;
    if (e < E) atomicAdd(&cnt[dst[e]], 1);
}

// per-block partial sums of cnt
__global__ __launch_bounds__(256) void scan_partial(const int* __restrict__ cnt, int N, int* __restrict__ aux)
{
    __shared__ int sm[4];
    int i = blockIdx.x * 256 + threadIdx.x;
    int v = (i < N) ? cnt[i] : 0;
#pragma unroll
    for (int o = 32; o > 0; o >>= 1) v += __shfl_down(v, o);
    if ((threadIdx.x & 63) == 0) sm[threadIdx.x >> 6] = v;
    __syncthreads();
    if (threadIdx.x == 0) aux[blockIdx.x] = sm[0] + sm[1] + sm[2] + sm[3];
}

// exclusive scan of aux (nb <= 1024), single block
__global__ __launch_bounds__(1024) void scan_aux(int* __restrict__ aux, int nb)
{
    __shared__ int s[1024];
    int t = threadIdx.x;
    int v = (t < nb) ? aux[t] : 0;
    s[t] = v;
    __syncthreads();
    for (int o = 1; o < 1024; o <<= 1) {
        int u = (t >= o) ? s[t - o] : 0;
        __syncthreads();
        s[t] += u;
        __syncthreads();
    }
    if (t < nb) aux[t] = t ? s[t - 1] : 0;
}

// rowptr[i] = exclusive prefix; rowptr[N] = total
__global__ __launch_bounds__(256) void scan_write(const int* __restrict__ cnt, const int* __restrict__ aux,
                                                  int N, int* __restrict__ rowptr)
{
    __shared__ int s[256];
    int t = threadIdx.x;
    int i = blockIdx.x * 256 + t;
    int v = (i < N) ? cnt[i] : 0;
    s[t] = v;
    __syncthreads();
    for (int o = 1; o < 256; o <<= 1) {
        int u = (t >= o) ? s[t - o] : 0;
        __syncthreads();
        s[t] += u;
        __syncthreads();
    }
    int excl = aux[blockIdx.x] + s[t] - v;
    if (i < N) rowptr[i] = excl;
    if (i == N - 1) rowptr[N] = excl + v;
}

__global__ __launch_bounds__(256) void copy_int(const int* __restrict__ a, int* __restrict__ b, int n)
{
    int i = blockIdx.x * blockDim.x + threadIdx.x;
    if (i < n) b[i] = a[i];
}

// place each edge into its dst bucket
__global__ __launch_bounds__(256) void scatter_csr(const int* __restrict__ src, const int* __restrict__ dst,
                                                   const float* __restrict__ ev, int E, int* __restrict__ cursor,
                                                   int* __restrict__ srcs, float* __restrict__ evs)
{
    int e = blockIdx.x * blockDim.x + threadIdx.x;
    if (e >= E) return;
    int p = atomicAdd(&cursor[dst[e]], 1);
    srcs[p] = src[e];
    evs[p] = ev[e];
}

// ---------------- fused softmax + aggregation, one wave per dst node ----------------
__global__ __launch_bounds__(256) void csr_agg(const int* __restrict__ rowptr, const int* __restrict__ srcs,
                                               const float* __restrict__ evs, const float* __restrict__ ssrc,
                                               const float* __restrict__ sdst, const float* __restrict__ h,
                                               float* __restrict__ out, int N)
{
    int n = (blockIdx.x * 256 + threadIdx.x) >> 6;   // one wave per node
    int lane = threadIdx.x & 63;
    if (n >= N) return;
    int beg = rowptr[n], end = rowptr[n + 1];
    float sd = sdst[n];
    float m = -INFINITY, den = 0.f;
    float ax = 0.f, ay = 0.f;
    for (int base = beg; base < end; base += 64) {
        int cnt = min(64, end - base);
        int sidx = 0; float l = -INFINITY, evv = 0.f;
        if (lane < cnt) {
            sidx = srcs[base + lane];
            evv = evs[base + lane];
            float ll = ssrc[sidx] + sd;
            l = ll >= 0.f ? ll : 0.2f * ll;
        }
        float cm = l;
#pragma unroll
        for (int o = 32; o > 0; o >>= 1) cm = fmaxf(cm, __shfl_xor(cm, o));
        float nm = fmaxf(m, cm);
        float sc = __expf(m - nm);       // first chunk: exp(-inf)=0, den/acc already 0
        den *= sc; ax *= sc; ay *= sc;
        float p = (lane < cnt) ? __expf(l - nm) * evv : 0.f;
        float ps = p;
#pragma unroll
        for (int o = 32; o > 0; o >>= 1) ps += __shfl_xor(ps, o);
        den += ps;
        for (int k = 0; k < cnt; ++k) {
            float c = __shfl(p, k);
            int s = __shfl(sidx, k);
            const float2 hv = *reinterpret_cast<const float2*>(&h[(size_t)s * DIM + lane * 2]);
            ax = fmaf(hv.x, c, ax);
            ay = fmaf(hv.y, c, ay);
        }
        m = nm;
    }
    float inv = 1.f / (den + 1e-16f);
    float2 o2 = { ax * inv, ay * inv };
    *reinterpret_cast<float2*>(&out[(size_t)n * DIM + lane * 2]) = o2;
}

// out = [elu(u[user_id]) ; elu(it[item_id])]
__global__ __launch_bounds__(256) void gather_out(const int* __restrict__ uid, const int* __restrict__ iid,
                                                  const float* __restrict__ u, const float* __restrict__ it,
                                                  float* __restrict__ out, int B)
{
    int t = blockIdx.x * blockDim.x + threadIdx.x;
    int total = B * DIM;
    if (t < total) {
        int b = t >> 7, j = t & 127;
        out[t] = elu_f(u[(size_t)uid[b] * DIM + j]);
    } else if (t < 2 * total) {
        int tt = t - total;
        int b = tt >> 7, j = tt & 127;
        out[t] = elu_f(it[(size_t)iid[b] * DIM + j]);
    }
}

extern "C" void kernel_launch(void* const* d_in, const int* in_sizes, int n_in,
                              void* d_out, int out_size, void* d_ws, size_t ws_size,
                              hipStream_t stream)
{
    const int*   uedg    = (const int*)d_in[0];
    const int*   iedg    = (const int*)d_in[1];
    const int*   user_id = (const int*)d_in[2];
    const int*   item_id = (const int*)d_in[3];
    const float* uval    = (const float*)d_in[4];
    const float* ival    = (const float*)d_in[5];
    const float* umat    = (const float*)d_in[6];
    const float* imat    = (const float*)d_in[7];
    const float* W_u1 = (const float*)d_in[8];
    const float* as_u1 = (const float*)d_in[9];
    const float* ad_u1 = (const float*)d_in[10];
    const float* W_u2 = (const float*)d_in[11];
    const float* as_u2 = (const float*)d_in[12];
    const float* ad_u2 = (const float*)d_in[13];
    const float* W_i1 = (const float*)d_in[14];
    const float* as_i1 = (const float*)d_in[15];
    const float* ad_i1 = (const float*)d_in[16];
    const float* W_i2 = (const float*)d_in[17];
    const float* as_i2 = (const float*)d_in[18];
    const float* ad_i2 = (const float*)d_in[19];

    const int EU = in_sizes[0] / 2;     // 400000
    const int EI = in_sizes[1] / 2;     // 200000
    const int B  = in_sizes[2];         // 4096
    const int NU = in_sizes[6] / DIM;   // 100000
    const int NI = in_sizes[7] / DIM;   // 50000

    float* h      = (float*)d_ws;                       // NU*DIM
    float* xb_u   = h    + (size_t)NU * DIM;            // NU*DIM
    float* xb_i   = xb_u + (size_t)NU * DIM;            // NI*DIM
    float* ssrc   = xb_i + (size_t)NI * DIM;            // NU
    float* sdst   = ssrc + NU;                          // NU
    int*   u_rp   = (int*)(sdst + NU);                  // NU+1
    int*   i_rp   = u_rp + (NU + 1);                    // NI+1
    int*   u_srcs = i_rp + (NI + 1);                    // EU
    float* u_evs  = (float*)(u_srcs + EU);              // EU
    int*   i_srcs = (int*)(u_evs + EU);                 // EI
    float* i_evs  = (float*)(i_srcs + EI);              // EI
    int*   cursor = (int*)(i_evs + EI);                 // NU+1
    int*   cnt    = cursor + (NU + 1);                  // NU
    int*   aux    = cnt + NU;                           // 2048

    auto build_csr = [&](const int* ei, const float* evv, int N, int E,
                         int* rp, int* srcs, float* evs) {
        const int* srcp = ei;
        const int* dstp = ei + E;
        hipMemsetAsync(cnt, 0, (size_t)N * 4, stream);
        hist_kernel<<<(E + 255) / 256, 256, 0, stream>>>(dstp, E, cnt);
        int nb = (N + 255) / 256;
        scan_partial<<<nb, 256, 0, stream>>>(cnt, N, aux);
        scan_aux<<<1, 1024, 0, stream>>>(aux, nb);
        scan_write<<<nb, 256, 0, stream>>>(cnt, aux, N, rp);
        copy_int<<<(N + 256) / 256, 256, 0, stream>>>(rp, cursor, N + 1);
        scatter_csr<<<(E + 255) / 256, 256, 0, stream>>>(srcp, dstp, evv, E, cursor, srcs, evs);
    };

    build_csr(uedg, uval, NU, EU, u_rp, u_srcs, u_evs);
    build_csr(iedg, ival, NI, EI, i_rp, i_srcs, i_evs);

    auto layer = [&](const float* x, const int* rp, const int* srcs, const float* evs,
                     const float* W, const float* as, const float* ad,
                     float* outb, int N, bool applyElu) {
        if (applyElu)
            gemm_s<1><<<512, 256, 0, stream>>>(x, W, as, ad, h, ssrc, sdst, N);
        else
            gemm_s<0><<<512, 256, 0, stream>>>(x, W, as, ad, h, ssrc, sdst, N);
        csr_agg<<<(N + 3) / 4, 256, 0, stream>>>(rp, srcs, evs, ssrc, sdst, h, outb, N);
    };

    // Layer order mirrors the reference: i1, u1, i2, u2
    layer(imat, i_rp, i_srcs, i_evs, W_i1, as_i1, ad_i1, xb_i, NI, false);
    layer(umat, u_rp, u_srcs, u_evs, W_u1, as_u1, ad_u1, xb_u, NU, false);
    layer(xb_i, i_rp, i_srcs, i_evs, W_i2, as_i2, ad_i2, xb_i, NI, true);
    layer(xb_u, u_rp, u_srcs, u_evs, W_u2, as_u2, ad_u2, xb_u, NU, true);

    int total = 2 * B * DIM;
    gather_out<<<(total + 255) / 256, 256, 0, stream>>>(user_id, item_id, xb_u, xb_i, (float*)d_out, B);
}

// Round 3
// 356.380 us; speedup vs baseline: 8.1436x; 2.5950x over previous
//
#include <hip/hip_runtime.h>
#include <hip/hip_bf16.h>

#define DIM 128

typedef short bf16x8 __attribute__((ext_vector_type(8)));
typedef float f32x4  __attribute__((ext_vector_type(4)));

__device__ __forceinline__ float elu_f(float x) { return x > 0.f ? x : expm1f(x); }

__device__ __forceinline__ short f2bf(float f) {
    unsigned u = __float_as_uint(f);
    unsigned r = (u + 0x7FFFu + ((u >> 16) & 1u)) >> 16;   // RNE
    return (short)r;
}

// h = elu?(x) @ W  via bf16 MFMA; fused s_src[n]=h[n]·a_src, s_dst[n]=h[n]·a_dst
// Block: 256 thr (4 waves). Tile: 64 rows x 128 cols. Wave w owns cols [32w,32w+32).
template<int APPLY_ELU>
__global__ __launch_bounds__(256) void gemm_mfma(const float* __restrict__ x, const float* __restrict__ W,
                                                 const float* __restrict__ a_src, const float* __restrict__ a_dst,
                                                 float* __restrict__ h, float* __restrict__ s_src,
                                                 float* __restrict__ s_dst, int N)
{
    __shared__ short xs[64 * 128];          // 16 KB bf16 tile, XOR-swizzled rows
    __shared__ float spart[2][4][64];       // [src/dst][wave][row]
    const int t  = threadIdx.x;
    const int wv = t >> 6;
    const int l  = t & 63;
    const int lo = l & 15;
    const int hi = l >> 4;

    // ---- W fragments in registers: wf[kb][cb2], B-layout lane l: k = kb*32+hi*8+j, col = wv*32+cb2*16+lo
    bf16x8 wf[4][2];
#pragma unroll
    for (int cb2 = 0; cb2 < 2; ++cb2) {
        const int col = wv * 32 + cb2 * 16 + lo;
#pragma unroll
        for (int kb = 0; kb < 4; ++kb) {
            bf16x8 f;
#pragma unroll
            for (int j = 0; j < 8; ++j)
                f[j] = f2bf(W[(kb * 32 + hi * 8 + j) * DIM + col]);
            wf[kb][cb2] = f;
        }
    }
    const float as0 = a_src[wv * 32 + lo],      as1 = a_src[wv * 32 + 16 + lo];
    const float ad0 = a_dst[wv * 32 + lo],      ad1 = a_dst[wv * 32 + 16 + lo];

    for (int r0 = blockIdx.x * 64; r0 < N; r0 += gridDim.x * 64) {
        __syncthreads();
        // ---- stage 64x128 fp32 -> bf16 LDS, swizzled: byte = row*256 + ((uc*16) ^ ((row&7)<<4))
#pragma unroll
        for (int i = 0; i < 4; ++i) {
            int unit = i * 256 + t;           // 1024 units of 8 bf16
            int row = unit >> 4, uc = unit & 15;
            int gr = r0 + row;
            float v[8] = {0,0,0,0,0,0,0,0};
            if (gr < N) {
                const float4* p = reinterpret_cast<const float4*>(&x[(size_t)gr * DIM + uc * 8]);
                float4 v0 = p[0], v1 = p[1];
                v[0]=v0.x; v[1]=v0.y; v[2]=v0.z; v[3]=v0.w;
                v[4]=v1.x; v[5]=v1.y; v[6]=v1.z; v[7]=v1.w;
                if (APPLY_ELU) {
#pragma unroll
                    for (int j = 0; j < 8; ++j) v[j] = elu_f(v[j]);
                }
            }
            bf16x8 bv;
#pragma unroll
            for (int j = 0; j < 8; ++j) bv[j] = f2bf(v[j]);
            int byte = row * 256 + ((uc * 16) ^ ((row & 7) << 4));
            *reinterpret_cast<bf16x8*>(reinterpret_cast<char*>(xs) + byte) = bv;
        }
        __syncthreads();

        // ---- compute: 4 row-blocks of 16
#pragma unroll
        for (int rb = 0; rb < 4; ++rb) {
            const int arow = rb * 16 + lo;    // A row this lane reads
            bf16x8 a[4];
#pragma unroll
            for (int kb = 0; kb < 4; ++kb) {
                int byte = arow * 256 + ((kb * 64 + hi * 16) ^ ((arow & 7) << 4));
                a[kb] = *reinterpret_cast<const bf16x8*>(reinterpret_cast<const char*>(xs) + byte);
            }
            f32x4 acc0 = {0.f,0.f,0.f,0.f}, acc1 = {0.f,0.f,0.f,0.f};
#pragma unroll
            for (int kb = 0; kb < 4; ++kb) {
                acc0 = __builtin_amdgcn_mfma_f32_16x16x32_bf16(a[kb], wf[kb][0], acc0, 0, 0, 0);
                acc1 = __builtin_amdgcn_mfma_f32_16x16x32_bf16(a[kb], wf[kb][1], acc1, 0, 0, 0);
            }
            // store h: lane holds rows rb*16 + hi*4 + i, cols wv*32 + cb2*16 + lo
#pragma unroll
            for (int i = 0; i < 4; ++i) {
                int row = r0 + rb * 16 + hi * 4 + i;
                if (row < N) {
                    h[(size_t)row * DIM + wv * 32 + lo]      = acc0[i];
                    h[(size_t)row * DIM + wv * 32 + 16 + lo] = acc1[i];
                }
            }
            // fused per-row dot with a_src/a_dst: reduce over the 16 cols (low-4 lane bits)
#pragma unroll
            for (int i = 0; i < 4; ++i) {
                float vs = acc0[i] * as0 + acc1[i] * as1;
                float vd = acc0[i] * ad0 + acc1[i] * ad1;
#pragma unroll
                for (int o = 8; o > 0; o >>= 1) {
                    vs += __shfl_xor(vs, o);
                    vd += __shfl_xor(vd, o);
                }
                if (lo == 0) {
                    spart[0][wv][rb * 16 + hi * 4 + i] = vs;
                    spart[1][wv][rb * 16 + hi * 4 + i] = vd;
                }
            }
        }
        __syncthreads();
        if (t < 64) {
            int row = r0 + t;
            if (row < N) s_src[row] = spart[0][0][t] + spart[0][1][t] + spart[0][2][t] + spart[0][3][t];
        } else if (t < 128) {
            int tt = t - 64;
            int row = r0 + tt;
            if (row < N) s_dst[row] = spart[1][0][tt] + spart[1][1][tt] + spart[1][2][tt] + spart[1][3][tt];
        }
    }
}

// ---------------- CSR build (once per graph per launch) ----------------

__global__ __launch_bounds__(256) void hist_kernel(const int* __restrict__ dst, int E, int* __restrict__ cnt)
{
    int e = blockIdx.x * blockDim.x + threadIdx.x;
    if (e < E) atomicAdd(&cnt[dst[e]], 1);
}

__global__ __launch_bounds__(256) void scan_partial(const int* __restrict__ cnt, int N, int* __restrict__ aux)
{
    __shared__ int sm[4];
    int i = blockIdx.x * 256 + threadIdx.x;
    int v = (i < N) ? cnt[i] : 0;
#pragma unroll
    for (int o = 32; o > 0; o >>= 1) v += __shfl_down(v, o);
    if ((threadIdx.x & 63) == 0) sm[threadIdx.x >> 6] = v;
    __syncthreads();
    if (threadIdx.x == 0) aux[blockIdx.x] = sm[0] + sm[1] + sm[2] + sm[3];
}

__global__ __launch_bounds__(1024) void scan_aux(int* __restrict__ aux, int nb)
{
    __shared__ int s[1024];
    int t = threadIdx.x;
    int v = (t < nb) ? aux[t] : 0;
    s[t] = v;
    __syncthreads();
    for (int o = 1; o < 1024; o <<= 1) {
        int u = (t >= o) ? s[t - o] : 0;
        __syncthreads();
        s[t] += u;
        __syncthreads();
    }
    if (t < nb) aux[t] = t ? s[t - 1] : 0;
}

__global__ __launch_bounds__(256) void scan_write(const int* __restrict__ cnt, const int* __restrict__ aux,
                                                  int N, int* __restrict__ rowptr)
{
    __shared__ int s[256];
    int t = threadIdx.x;
    int i = blockIdx.x * 256 + t;
    int v = (i < N) ? cnt[i] : 0;
    s[t] = v;
    __syncthreads();
    for (int o = 1; o < 256; o <<= 1) {
        int u = (t >= o) ? s[t - o] : 0;
        __syncthreads();
        s[t] += u;
        __syncthreads();
    }
    int excl = aux[blockIdx.x] + s[t] - v;
    if (i < N) rowptr[i] = excl;
    if (i == N - 1) rowptr[N] = excl + v;
}

__global__ __launch_bounds__(256) void copy_int(const int* __restrict__ a, int* __restrict__ b, int n)
{
    int i = blockIdx.x * blockDim.x + threadIdx.x;
    if (i < n) b[i] = a[i];
}

__global__ __launch_bounds__(256) void scatter_csr(const int* __restrict__ src, const int* __restrict__ dst,
                                                   const float* __restrict__ ev, int E, int* __restrict__ cursor,
                                                   int* __restrict__ srcs, float* __restrict__ evs)
{
    int e = blockIdx.x * blockDim.x + threadIdx.x;
    if (e >= E) return;
    int p = atomicAdd(&cursor[dst[e]], 1);
    srcs[p] = src[e];
    evs[p] = ev[e];
}

// ---------------- fused softmax + aggregation, one wave per dst node ----------------
__global__ __launch_bounds__(256) void csr_agg(const int* __restrict__ rowptr, const int* __restrict__ srcs,
                                               const float* __restrict__ evs, const float* __restrict__ ssrc,
                                               const float* __restrict__ sdst, const float* __restrict__ h,
                                               float* __restrict__ out, int N)
{
    int n = (blockIdx.x * 256 + threadIdx.x) >> 6;   // one wave per node
    int lane = threadIdx.x & 63;
    if (n >= N) return;
    int beg = rowptr[n], end = rowptr[n + 1];
    float sd = sdst[n];
    float m = -INFINITY, den = 0.f;
    float ax = 0.f, ay = 0.f;
    for (int base = beg; base < end; base += 64) {
        int cnt = min(64, end - base);
        int sidx = 0; float l = -INFINITY, evv = 0.f;
        if (lane < cnt) {
            sidx = srcs[base + lane];
            evv = evs[base + lane];
            float ll = ssrc[sidx] + sd;
            l = ll >= 0.f ? ll : 0.2f * ll;
        }
        float cm = l;
#pragma unroll
        for (int o = 32; o > 0; o >>= 1) cm = fmaxf(cm, __shfl_xor(cm, o));
        float nm = fmaxf(m, cm);
        float sc = __expf(m - nm);       // first chunk: exp(-inf)=0, den/acc already 0
        den *= sc; ax *= sc; ay *= sc;
        float p = (lane < cnt) ? __expf(l - nm) * evv : 0.f;
        float ps = p;
#pragma unroll
        for (int o = 32; o > 0; o >>= 1) ps += __shfl_xor(ps, o);
        den += ps;
        for (int k = 0; k < cnt; ++k) {
            float c = __shfl(p, k);
            int s = __shfl(sidx, k);
            const float2 hv = *reinterpret_cast<const float2*>(&h[(size_t)s * DIM + lane * 2]);
            ax = fmaf(hv.x, c, ax);
            ay = fmaf(hv.y, c, ay);
        }
        m = nm;
    }
    float inv = 1.f / (den + 1e-16f);
    float2 o2 = { ax * inv, ay * inv };
    *reinterpret_cast<float2*>(&out[(size_t)n * DIM + lane * 2]) = o2;
}

// out = [elu(u[user_id]) ; elu(it[item_id])]
__global__ __launch_bounds__(256) void gather_out(const int* __restrict__ uid, const int* __restrict__ iid,
                                                  const float* __restrict__ u, const float* __restrict__ it,
                                                  float* __restrict__ out, int B)
{
    int t = blockIdx.x * blockDim.x + threadIdx.x;
    int total = B * DIM;
    if (t < total) {
        int b = t >> 7, j = t & 127;
        out[t] = elu_f(u[(size_t)uid[b] * DIM + j]);
    } else if (t < 2 * total) {
        int tt = t - total;
        int b = tt >> 7, j = tt & 127;
        out[t] = elu_f(it[(size_t)iid[b] * DIM + j]);
    }
}

extern "C" void kernel_launch(void* const* d_in, const int* in_sizes, int n_in,
                              void* d_out, int out_size, void* d_ws, size_t ws_size,
                              hipStream_t stream)
{
    const int*   uedg    = (const int*)d_in[0];
    const int*   iedg    = (const int*)d_in[1];
    const int*   user_id = (const int*)d_in[2];
    const int*   item_id = (const int*)d_in[3];
    const float* uval    = (const float*)d_in[4];
    const float* ival    = (const float*)d_in[5];
    const float* umat    = (const float*)d_in[6];
    const float* imat    = (const float*)d_in[7];
    const float* W_u1 = (const float*)d_in[8];
    const float* as_u1 = (const float*)d_in[9];
    const float* ad_u1 = (const float*)d_in[10];
    const float* W_u2 = (const float*)d_in[11];
    const float* as_u2 = (const float*)d_in[12];
    const float* ad_u2 = (const float*)d_in[13];
    const float* W_i1 = (const float*)d_in[14];
    const float* as_i1 = (const float*)d_in[15];
    const float* ad_i1 = (const float*)d_in[16];
    const float* W_i2 = (const float*)d_in[17];
    const float* as_i2 = (const float*)d_in[18];
    const float* ad_i2 = (const float*)d_in[19];

    const int EU = in_sizes[0] / 2;     // 400000
    const int EI = in_sizes[1] / 2;     // 200000
    const int B  = in_sizes[2];         // 4096
    const int NU = in_sizes[6] / DIM;   // 100000
    const int NI = in_sizes[7] / DIM;   // 50000

    float* h      = (float*)d_ws;                       // NU*DIM
    float* xb_u   = h    + (size_t)NU * DIM;            // NU*DIM
    float* xb_i   = xb_u + (size_t)NU * DIM;            // NI*DIM
    float* ssrc   = xb_i + (size_t)NI * DIM;            // NU
    float* sdst   = ssrc + NU;                          // NU
    int*   u_rp   = (int*)(sdst + NU);                  // NU+1
    int*   i_rp   = u_rp + (NU + 1);                    // NI+1
    int*   u_srcs = i_rp + (NI + 1);                    // EU
    float* u_evs  = (float*)(u_srcs + EU);              // EU
    int*   i_srcs = (int*)(u_evs + EU);                 // EI
    float* i_evs  = (float*)(i_srcs + EI);              // EI
    int*   cursor = (int*)(i_evs + EI);                 // NU+1
    int*   cnt    = cursor + (NU + 1);                  // NU
    int*   aux    = cnt + NU;                           // 2048

    auto build_csr = [&](const int* ei, const float* evv, int N, int E,
                         int* rp, int* srcs, float* evs) {
        const int* srcp = ei;
        const int* dstp = ei + E;
        hipMemsetAsync(cnt, 0, (size_t)N * 4, stream);
        hist_kernel<<<(E + 255) / 256, 256, 0, stream>>>(dstp, E, cnt);
        int nb = (N + 255) / 256;
        scan_partial<<<nb, 256, 0, stream>>>(cnt, N, aux);
        scan_aux<<<1, 1024, 0, stream>>>(aux, nb);
        scan_write<<<nb, 256, 0, stream>>>(cnt, aux, N, rp);
        copy_int<<<(N + 256) / 256, 256, 0, stream>>>(rp, cursor, N + 1);
        scatter_csr<<<(E + 255) / 256, 256, 0, stream>>>(srcp, dstp, evv, E, cursor, srcs, evs);
    };

    build_csr(uedg, uval, NU, EU, u_rp, u_srcs, u_evs);
    build_csr(iedg, ival, NI, EI, i_rp, i_srcs, i_evs);

    auto layer = [&](const float* x, const int* rp, const int* srcs, const float* evs,
                     const float* W, const float* as, const float* ad,
                     float* outb, int N, bool applyElu) {
        int grid = (N + 63) / 64;
        if (applyElu)
            gemm_mfma<1><<<grid, 256, 0, stream>>>(x, W, as, ad, h, ssrc, sdst, N);
        else
            gemm_mfma<0><<<grid, 256, 0, stream>>>(x, W, as, ad, h, ssrc, sdst, N);
        csr_agg<<<(N + 3) / 4, 256, 0, stream>>>(rp, srcs, evs, ssrc, sdst, h, outb, N);
    };

    // Layer order mirrors the reference: i1, u1, i2, u2
    layer(imat, i_rp, i_srcs, i_evs, W_i1, as_i1, ad_i1, xb_i, NI, false);
    layer(umat, u_rp, u_srcs, u_evs, W_u1, as_u1, ad_u1, xb_u, NU, false);
    layer(xb_i, i_rp, i_srcs, i_evs, W_i2, as_i2, ad_i2, xb_i, NI, true);
    layer(xb_u, u_rp, u_srcs, u_evs, W_u2, as_u2, ad_u2, xb_u, NU, true);

    int total = 2 * B * DIM;
    gather_out<<<(total + 255) / 256, 256, 0, stream>>>(user_id, item_id, xb_u, xb_i, (float*)d_out, B);
}

// Round 4
// 275.906 us; speedup vs baseline: 10.5189x; 1.2917x over previous
//
#include <hip/hip_runtime.h>
#include <hip/hip_bf16.h>

#define DIM 128

typedef short bf16x8 __attribute__((ext_vector_type(8)));
typedef float f32x4  __attribute__((ext_vector_type(4)));

__device__ __forceinline__ float elu_f(float x) { return x > 0.f ? x : expm1f(x); }

__device__ __forceinline__ unsigned short f2bf(float f) {
    unsigned u = __float_as_uint(f);
    unsigned r = (u + 0x7FFFu + ((u >> 16) & 1u)) >> 16;   // RNE
    return (unsigned short)r;
}
__device__ __forceinline__ float bf2f(unsigned short b) {
    return __uint_as_float(((unsigned)b) << 16);
}

// h(bf16) = elu?(x) @ W  via bf16 MFMA; fused s_src[n]=h[n]·a_src, s_dst[n]=h[n]·a_dst
// Block: 256 thr (4 waves). Tile: 64 rows x 128 cols. Wave w owns cols [32w,32w+32).
template<int APPLY_ELU>
__global__ __launch_bounds__(256) void gemm_mfma(const float* __restrict__ x, const float* __restrict__ W,
                                                 const float* __restrict__ a_src, const float* __restrict__ a_dst,
                                                 unsigned short* __restrict__ h, float* __restrict__ s_src,
                                                 float* __restrict__ s_dst, int N)
{
    __shared__ short xs[64 * 128];          // 16 KB bf16 tile, XOR-swizzled rows
    __shared__ float spart[2][4][64];       // [src/dst][wave][row]
    const int t  = threadIdx.x;
    const int wv = t >> 6;
    const int l  = t & 63;
    const int lo = l & 15;
    const int hi = l >> 4;

    // ---- W fragments in registers: B-layout lane l: k = kb*32+hi*8+j, col = wv*32+cb2*16+lo
    bf16x8 wf[4][2];
#pragma unroll
    for (int cb2 = 0; cb2 < 2; ++cb2) {
        const int col = wv * 32 + cb2 * 16 + lo;
#pragma unroll
        for (int kb = 0; kb < 4; ++kb) {
            bf16x8 f;
#pragma unroll
            for (int j = 0; j < 8; ++j)
                f[j] = (short)f2bf(W[(kb * 32 + hi * 8 + j) * DIM + col]);
            wf[kb][cb2] = f;
        }
    }
    const float as0 = a_src[wv * 32 + lo],      as1 = a_src[wv * 32 + 16 + lo];
    const float ad0 = a_dst[wv * 32 + lo],      ad1 = a_dst[wv * 32 + 16 + lo];

    for (int r0 = blockIdx.x * 64; r0 < N; r0 += gridDim.x * 64) {
        __syncthreads();
        // ---- stage 64x128 fp32 -> bf16 LDS, swizzled: byte = row*256 + ((uc*16) ^ ((row&7)<<4))
#pragma unroll
        for (int i = 0; i < 4; ++i) {
            int unit = i * 256 + t;           // 1024 units of 8 bf16
            int row = unit >> 4, uc = unit & 15;
            int gr = r0 + row;
            float v[8] = {0,0,0,0,0,0,0,0};
            if (gr < N) {
                const float4* p = reinterpret_cast<const float4*>(&x[(size_t)gr * DIM + uc * 8]);
                float4 v0 = p[0], v1 = p[1];
                v[0]=v0.x; v[1]=v0.y; v[2]=v0.z; v[3]=v0.w;
                v[4]=v1.x; v[5]=v1.y; v[6]=v1.z; v[7]=v1.w;
                if (APPLY_ELU) {
#pragma unroll
                    for (int j = 0; j < 8; ++j) v[j] = elu_f(v[j]);
                }
            }
            bf16x8 bv;
#pragma unroll
            for (int j = 0; j < 8; ++j) bv[j] = (short)f2bf(v[j]);
            int byte = row * 256 + ((uc * 16) ^ ((row & 7) << 4));
            *reinterpret_cast<bf16x8*>(reinterpret_cast<char*>(xs) + byte) = bv;
        }
        __syncthreads();

        // ---- compute: 4 row-blocks of 16
#pragma unroll
        for (int rb = 0; rb < 4; ++rb) {
            const int arow = rb * 16 + lo;    // A row this lane reads
            bf16x8 a[4];
#pragma unroll
            for (int kb = 0; kb < 4; ++kb) {
                int byte = arow * 256 + ((kb * 64 + hi * 16) ^ ((arow & 7) << 4));
                a[kb] = *reinterpret_cast<const bf16x8*>(reinterpret_cast<const char*>(xs) + byte);
            }
            f32x4 acc0 = {0.f,0.f,0.f,0.f}, acc1 = {0.f,0.f,0.f,0.f};
#pragma unroll
            for (int kb = 0; kb < 4; ++kb) {
                acc0 = __builtin_amdgcn_mfma_f32_16x16x32_bf16(a[kb], wf[kb][0], acc0, 0, 0, 0);
                acc1 = __builtin_amdgcn_mfma_f32_16x16x32_bf16(a[kb], wf[kb][1], acc1, 0, 0, 0);
            }
            // store h (bf16): lane holds rows rb*16 + hi*4 + i, cols wv*32 + lo and +16
#pragma unroll
            for (int i = 0; i < 4; ++i) {
                int row = r0 + rb * 16 + hi * 4 + i;
                if (row < N) {
                    h[(size_t)row * DIM + wv * 32 + lo]      = f2bf(acc0[i]);
                    h[(size_t)row * DIM + wv * 32 + 16 + lo] = f2bf(acc1[i]);
                }
            }
            // fused per-row dot with a_src/a_dst: reduce over the 16 cols (low-4 lane bits)
#pragma unroll
            for (int i = 0; i < 4; ++i) {
                float vs = acc0[i] * as0 + acc1[i] * as1;
                float vd = acc0[i] * ad0 + acc1[i] * ad1;
#pragma unroll
                for (int o = 8; o > 0; o >>= 1) {
                    vs += __shfl_xor(vs, o);
                    vd += __shfl_xor(vd, o);
                }
                if (lo == 0) {
                    spart[0][wv][rb * 16 + hi * 4 + i] = vs;
                    spart[1][wv][rb * 16 + hi * 4 + i] = vd;
                }
            }
        }
        __syncthreads();
        if (t < 64) {
            int row = r0 + t;
            if (row < N) s_src[row] = spart[0][0][t] + spart[0][1][t] + spart[0][2][t] + spart[0][3][t];
        } else if (t < 128) {
            int tt = t - 64;
            int row = r0 + tt;
            if (row < N) s_dst[row] = spart[1][0][tt] + spart[1][1][tt] + spart[1][2][tt] + spart[1][3][tt];
        }
    }
}

// ---------------- CSR build (once per graph per launch) ----------------

__global__ __launch_bounds__(256) void hist_kernel(const int* __restrict__ dst, int E, int* __restrict__ cnt)
{
    int e = blockIdx.x * blockDim.x + threadIdx.x;
    if (e < E) atomicAdd(&cnt[dst[e]], 1);
}

__global__ __launch_bounds__(256) void scan_partial(const int* __restrict__ cnt, int N, int* __restrict__ aux)
{
    __shared__ int sm[4];
    int i = blockIdx.x * 256 + threadIdx.x;
    int v = (i < N) ? cnt[i] : 0;
#pragma unroll
    for (int o = 32; o > 0; o >>= 1) v += __shfl_down(v, o);
    if ((threadIdx.x & 63) == 0) sm[threadIdx.x >> 6] = v;
    __syncthreads();
    if (threadIdx.x == 0) aux[blockIdx.x] = sm[0] + sm[1] + sm[2] + sm[3];
}

__global__ __launch_bounds__(1024) void scan_aux(int* __restrict__ aux, int nb)
{
    __shared__ int s[1024];
    int t = threadIdx.x;
    int v = (t < nb) ? aux[t] : 0;
    s[t] = v;
    __syncthreads();
    for (int o = 1; o < 1024; o <<= 1) {
        int u = (t >= o) ? s[t - o] : 0;
        __syncthreads();
        s[t] += u;
        __syncthreads();
    }
    if (t < nb) aux[t] = t ? s[t - 1] : 0;
}

__global__ __launch_bounds__(256) void scan_write(const int* __restrict__ cnt, const int* __restrict__ aux,
                                                  int N, int* __restrict__ rowptr)
{
    __shared__ int s[256];
    int t = threadIdx.x;
    int i = blockIdx.x * 256 + t;
    int v = (i < N) ? cnt[i] : 0;
    s[t] = v;
    __syncthreads();
    for (int o = 1; o < 256; o <<= 1) {
        int u = (t >= o) ? s[t - o] : 0;
        __syncthreads();
        s[t] += u;
        __syncthreads();
    }
    int excl = aux[blockIdx.x] + s[t] - v;
    if (i < N) rowptr[i] = excl;
    if (i == N - 1) rowptr[N] = excl + v;
}

__global__ __launch_bounds__(256) void copy_int(const int* __restrict__ a, int* __restrict__ b, int n)
{
    int i = blockIdx.x * blockDim.x + threadIdx.x;
    if (i < n) b[i] = a[i];
}

__global__ __launch_bounds__(256) void scatter_csr(const int* __restrict__ src, const int* __restrict__ dst,
                                                   const float* __restrict__ ev, int E, int* __restrict__ cursor,
                                                   int* __restrict__ srcs, float* __restrict__ evs)
{
    int e = blockIdx.x * blockDim.x + threadIdx.x;
    if (e >= E) return;
    int p = atomicAdd(&cursor[dst[e]], 1);
    srcs[p] = src[e];
    evs[p] = ev[e];
}

// ---------------- fused softmax + aggregation: 16 lanes per dst node ----------------
__global__ __launch_bounds__(256) void csr_agg16(const int* __restrict__ rowptr, const int* __restrict__ srcs,
                                                 const float* __restrict__ evs, const float* __restrict__ ssrc,
                                                 const float* __restrict__ sdst, const unsigned short* __restrict__ h,
                                                 float* __restrict__ out, int N)
{
    int n = (blockIdx.x * 256 + threadIdx.x) >> 4;   // one 16-lane group per node
    int l16 = threadIdx.x & 15;
    if (n >= N) return;
    int beg = rowptr[n], end = rowptr[n + 1];
    float sd = sdst[n];
    float m = -INFINITY, den = 0.f;
    float acc[8] = {0,0,0,0,0,0,0,0};
    for (int base = beg; base < end; base += 16) {
        int cnt = min(16, end - base);
        int sidx = 0; float l = -INFINITY, evv = 0.f;
        if (l16 < cnt) {
            sidx = srcs[base + l16];
            evv = evs[base + l16];
            float ll = ssrc[sidx] + sd;
            l = ll >= 0.f ? ll : 0.2f * ll;
        }
        float cm = l;
#pragma unroll
        for (int o = 8; o > 0; o >>= 1) cm = fmaxf(cm, __shfl_xor(cm, o, 16));
        float nm = fmaxf(m, cm);
        float sc = __expf(m - nm);       // first chunk: exp(-inf)=0, den/acc already 0
        den *= sc;
#pragma unroll
        for (int j = 0; j < 8; ++j) acc[j] *= sc;
        float p = (l16 < cnt) ? __expf(l - nm) * evv : 0.f;
        float ps = p;
#pragma unroll
        for (int o = 8; o > 0; o >>= 1) ps += __shfl_xor(ps, o, 16);
        den += ps;
        for (int k = 0; k < cnt; ++k) {
            float c = __shfl(p, k, 16);
            int s = __shfl(sidx, k, 16);
            const bf16x8 hv = *reinterpret_cast<const bf16x8*>(&h[(size_t)s * DIM + l16 * 8]);
#pragma unroll
            for (int j = 0; j < 8; ++j)
                acc[j] = fmaf(bf2f((unsigned short)hv[j]), c, acc[j]);
        }
        m = nm;
    }
    float inv = 1.f / (den + 1e-16f);
    float4 o0 = { acc[0]*inv, acc[1]*inv, acc[2]*inv, acc[3]*inv };
    float4 o1 = { acc[4]*inv, acc[5]*inv, acc[6]*inv, acc[7]*inv };
    float4* op = reinterpret_cast<float4*>(&out[(size_t)n * DIM + l16 * 8]);
    op[0] = o0;
    op[1] = o1;
}

// out = [elu(u[user_id]) ; elu(it[item_id])]
__global__ __launch_bounds__(256) void gather_out(const int* __restrict__ uid, const int* __restrict__ iid,
                                                  const float* __restrict__ u, const float* __restrict__ it,
                                                  float* __restrict__ out, int B)
{
    int t = blockIdx.x * blockDim.x + threadIdx.x;
    int total = B * DIM;
    if (t < total) {
        int b = t >> 7, j = t & 127;
        out[t] = elu_f(u[(size_t)uid[b] * DIM + j]);
    } else if (t < 2 * total) {
        int tt = t - total;
        int b = tt >> 7, j = tt & 127;
        out[t] = elu_f(it[(size_t)iid[b] * DIM + j]);
    }
}

extern "C" void kernel_launch(void* const* d_in, const int* in_sizes, int n_in,
                              void* d_out, int out_size, void* d_ws, size_t ws_size,
                              hipStream_t stream)
{
    const int*   uedg    = (const int*)d_in[0];
    const int*   iedg    = (const int*)d_in[1];
    const int*   user_id = (const int*)d_in[2];
    const int*   item_id = (const int*)d_in[3];
    const float* uval    = (const float*)d_in[4];
    const float* ival    = (const float*)d_in[5];
    const float* umat    = (const float*)d_in[6];
    const float* imat    = (const float*)d_in[7];
    const float* W_u1 = (const float*)d_in[8];
    const float* as_u1 = (const float*)d_in[9];
    const float* ad_u1 = (const float*)d_in[10];
    const float* W_u2 = (const float*)d_in[11];
    const float* as_u2 = (const float*)d_in[12];
    const float* ad_u2 = (const float*)d_in[13];
    const float* W_i1 = (const float*)d_in[14];
    const float* as_i1 = (const float*)d_in[15];
    const float* ad_i1 = (const float*)d_in[16];
    const float* W_i2 = (const float*)d_in[17];
    const float* as_i2 = (const float*)d_in[18];
    const float* ad_i2 = (const float*)d_in[19];

    const int EU = in_sizes[0] / 2;     // 400000
    const int EI = in_sizes[1] / 2;     // 200000
    const int B  = in_sizes[2];         // 4096
    const int NU = in_sizes[6] / DIM;   // 100000
    const int NI = in_sizes[7] / DIM;   // 50000

    unsigned short* h = (unsigned short*)d_ws;          // NU*DIM bf16
    float* xb_u   = (float*)(h + (size_t)NU * DIM);     // NU*DIM
    float* xb_i   = xb_u + (size_t)NU * DIM;            // NI*DIM
    float* ssrc   = xb_i + (size_t)NI * DIM;            // NU
    float* sdst   = ssrc + NU;                          // NU
    int*   u_rp   = (int*)(sdst + NU);                  // NU+1
    int*   i_rp   = u_rp + (NU + 1);                    // NI+1
    int*   u_srcs = i_rp + (NI + 1);                    // EU
    float* u_evs  = (float*)(u_srcs + EU);              // EU
    int*   i_srcs = (int*)(u_evs + EU);                 // EI
    float* i_evs  = (float*)(i_srcs + EI);              // EI
    int*   cursor = (int*)(i_evs + EI);                 // NU+1
    int*   cnt    = cursor + (NU + 1);                  // NU
    int*   aux    = cnt + NU;                           // 2048

    auto build_csr = [&](const int* ei, const float* evv, int N, int E,
                         int* rp, int* srcs, float* evs) {
        const int* srcp = ei;
        const int* dstp = ei + E;
        hipMemsetAsync(cnt, 0, (size_t)N * 4, stream);
        hist_kernel<<<(E + 255) / 256, 256, 0, stream>>>(dstp, E, cnt);
        int nb = (N + 255) / 256;
        scan_partial<<<nb, 256, 0, stream>>>(cnt, N, aux);
        scan_aux<<<1, 1024, 0, stream>>>(aux, nb);
        scan_write<<<nb, 256, 0, stream>>>(cnt, aux, N, rp);
        copy_int<<<(N + 256) / 256, 256, 0, stream>>>(rp, cursor, N + 1);
        scatter_csr<<<(E + 255) / 256, 256, 0, stream>>>(srcp, dstp, evv, E, cursor, srcs, evs);
    };

    build_csr(uedg, uval, NU, EU, u_rp, u_srcs, u_evs);
    build_csr(iedg, ival, NI, EI, i_rp, i_srcs, i_evs);

    auto layer = [&](const float* x, const int* rp, const int* srcs, const float* evs,
                     const float* W, const float* as, const float* ad,
                     float* outb, int N, bool applyElu) {
        int grid = (N + 63) / 64;
        if (applyElu)
            gemm_mfma<1><<<grid, 256, 0, stream>>>(x, W, as, ad, h, ssrc, sdst, N);
        else
            gemm_mfma<0><<<grid, 256, 0, stream>>>(x, W, as, ad, h, ssrc, sdst, N);
        csr_agg16<<<(N + 15) / 16, 256, 0, stream>>>(rp, srcs, evs, ssrc, sdst, h, outb, N);
    };

    // Layer order mirrors the reference: i1, u1, i2, u2
    layer(imat, i_rp, i_srcs, i_evs, W_i1, as_i1, ad_i1, xb_i, NI, false);
    layer(umat, u_rp, u_srcs, u_evs, W_u1, as_u1, ad_u1, xb_u, NU, false);
    layer(xb_i, i_rp, i_srcs, i_evs, W_i2, as_i2, ad_i2, xb_i, NI, true);
    layer(xb_u, u_rp, u_srcs, u_evs, W_u2, as_u2, ad_u2, xb_u, NU, true);

    int total = 2 * B * DIM;
    gather_out<<<(total + 255) / 256, 256, 0, stream>>>(user_id, item_id, xb_u, xb_i, (float*)d_out, B);
}

// Round 5
// 272.905 us; speedup vs baseline: 10.6346x; 1.0110x over previous
//
#include <hip/hip_runtime.h>
#include <hip/hip_bf16.h>

#define DIM 128

typedef short bf16x8 __attribute__((ext_vector_type(8)));
typedef float f32x4  __attribute__((ext_vector_type(4)));

__device__ __forceinline__ float elu_f(float x) { return x > 0.f ? x : expm1f(x); }

__device__ __forceinline__ unsigned short f2bfu(float f) {
    return __builtin_bit_cast(unsigned short, __float2bfloat16(f));   // RNE, fuses to v_cvt_pk_bf16_f32
}
__device__ __forceinline__ float bf2f(unsigned short b) {
    return __uint_as_float(((unsigned)b) << 16);
}

// ---------------- per-layer W prep: W_t[c][k] = bf16(W[k][c]); wa[0][k]=bf16(W·a_src)[k], wa[1][k]=... ----
// grid: 8 blocks x 256 thr; block b handles rows [16b, 16b+16)
__global__ __launch_bounds__(256) void prep_w(const float* __restrict__ W,
                                              const float* __restrict__ a_src, const float* __restrict__ a_dst,
                                              unsigned short* __restrict__ W_t, unsigned short* __restrict__ wa)
{
    __shared__ float as[DIM], ad[DIM];
    __shared__ float sr[4][2];
    const int t = threadIdx.x;
    if (t < DIM) as[t] = a_src[t];
    else ad[t - DIM] = a_dst[t - DIM];
    __syncthreads();
    const int half = t >> 7;            // row within pair
    const int c = t & 127;
    const int wv = t >> 6;
    const int k_end = blockIdx.x * 16 + 16;
    for (int k0 = blockIdx.x * 16; k0 < k_end; k0 += 2) {
        const int k = k0 + half;
        float w = W[k * DIM + c];
        W_t[c * DIM + k] = f2bfu(w);
        float vs = w * as[c], vd = w * ad[c];
#pragma unroll
        for (int o = 32; o > 0; o >>= 1) { vs += __shfl_down(vs, o); vd += __shfl_down(vd, o); }
        if ((t & 63) == 0) { sr[wv][0] = vs; sr[wv][1] = vd; }
        __syncthreads();
        if (t < 2) {
            const int kk = k0 + t;
            wa[kk]       = f2bfu(sr[2 * t][0] + sr[2 * t + 1][0]);
            wa[DIM + kk] = f2bfu(sr[2 * t][1] + sr[2 * t + 1][1]);
        }
        __syncthreads();
    }
}

// h(bf16) = elu?(x) @ W via bf16 MFMA; s_src/s_dst computed as extra MFMA columns (x @ wa).
// Block: 256 thr (4 waves). Tile: 64 rows x 128 cols. Wave w owns cols [32w,32w+32); wave w computes s for rows [16w,16w+16).
template<int APPLY_ELU>
__global__ __launch_bounds__(256) void gemm_mfma(const float* __restrict__ x, const unsigned short* __restrict__ W_t,
                                                 const unsigned short* __restrict__ wa,
                                                 unsigned short* __restrict__ h, float* __restrict__ s_src,
                                                 float* __restrict__ s_dst, int N)
{
    __shared__ short xs[64 * 128];          // 16 KB bf16 tile, XOR-swizzled rows
    const int t  = threadIdx.x;
    const int wv = t >> 6;
    const int l  = t & 63;
    const int lo = l & 15;
    const int hi = l >> 4;

    // ---- W fragments (bf16, pre-transposed): contiguous 16B loads
    bf16x8 wf[4][2];
#pragma unroll
    for (int cb2 = 0; cb2 < 2; ++cb2) {
        const unsigned short* base = W_t + (wv * 32 + cb2 * 16 + lo) * DIM + hi * 8;
#pragma unroll
        for (int kb = 0; kb < 4; ++kb)
            wf[kb][cb2] = *reinterpret_cast<const bf16x8*>(base + kb * 32);
    }
    // ---- s fragment: col 0 = wa_src, col 1 = wa_dst, cols 2-15 zero
    bf16x8 sfrag[4];
    if (lo < 2) {
        const unsigned short* sb = wa + lo * DIM + hi * 8;
#pragma unroll
        for (int kb = 0; kb < 4; ++kb)
            sfrag[kb] = *reinterpret_cast<const bf16x8*>(sb + kb * 32);
    } else {
#pragma unroll
        for (int kb = 0; kb < 4; ++kb) {
            bf16x8 z = { 0, 0, 0, 0, 0, 0, 0, 0 };
            sfrag[kb] = z;
        }
    }

    for (int r0 = blockIdx.x * 64; r0 < N; r0 += gridDim.x * 64) {
        __syncthreads();
        // ---- stage 64x128 fp32 -> bf16 LDS, swizzled: byte = row*256 + ((uc*16) ^ ((row&7)<<4))
#pragma unroll
        for (int i = 0; i < 4; ++i) {
            int unit = i * 256 + t;           // 1024 units of 8 bf16
            int row = unit >> 4, uc = unit & 15;
            int gr = r0 + row;
            float v[8] = {0,0,0,0,0,0,0,0};
            if (gr < N) {
                const float4* p = reinterpret_cast<const float4*>(&x[(size_t)gr * DIM + uc * 8]);
                float4 v0 = p[0], v1 = p[1];
                v[0]=v0.x; v[1]=v0.y; v[2]=v0.z; v[3]=v0.w;
                v[4]=v1.x; v[5]=v1.y; v[6]=v1.z; v[7]=v1.w;
                if (APPLY_ELU) {
#pragma unroll
                    for (int j = 0; j < 8; ++j) v[j] = elu_f(v[j]);
                }
            }
            bf16x8 bv;
#pragma unroll
            for (int j = 0; j < 8; ++j) bv[j] = (short)f2bfu(v[j]);
            int byte = row * 256 + ((uc * 16) ^ ((row & 7) << 4));
            *reinterpret_cast<bf16x8*>(reinterpret_cast<char*>(xs) + byte) = bv;
        }
        __syncthreads();

        // ---- compute: 4 row-blocks of 16
#pragma unroll
        for (int rb = 0; rb < 4; ++rb) {
            const int arow = rb * 16 + lo;    // A row this lane reads
            bf16x8 a[4];
#pragma unroll
            for (int kb = 0; kb < 4; ++kb) {
                int byte = arow * 256 + ((kb * 64 + hi * 16) ^ ((arow & 7) << 4));
                a[kb] = *reinterpret_cast<const bf16x8*>(reinterpret_cast<const char*>(xs) + byte);
            }
            f32x4 acc0 = {0.f,0.f,0.f,0.f}, acc1 = {0.f,0.f,0.f,0.f};
#pragma unroll
            for (int kb = 0; kb < 4; ++kb) {
                acc0 = __builtin_amdgcn_mfma_f32_16x16x32_bf16(a[kb], wf[kb][0], acc0, 0, 0, 0);
                acc1 = __builtin_amdgcn_mfma_f32_16x16x32_bf16(a[kb], wf[kb][1], acc1, 0, 0, 0);
            }
            // store h (bf16): lane holds rows rb*16 + hi*4 + i, cols wv*32 + lo and +16
#pragma unroll
            for (int i = 0; i < 4; ++i) {
                int row = r0 + rb * 16 + hi * 4 + i;
                if (row < N) {
                    h[(size_t)row * DIM + wv * 32 + lo]      = f2bfu(acc0[i]);
                    h[(size_t)row * DIM + wv * 32 + 16 + lo] = f2bfu(acc1[i]);
                }
            }
            // wave wv computes s for its own row-block via MFMA (cols 0,1 of x @ [wa_src|wa_dst|0..])
            if (rb == wv) {
                f32x4 acc_s = {0.f,0.f,0.f,0.f};
#pragma unroll
                for (int kb = 0; kb < 4; ++kb)
                    acc_s = __builtin_amdgcn_mfma_f32_16x16x32_bf16(a[kb], sfrag[kb], acc_s, 0, 0, 0);
#pragma unroll
                for (int i = 0; i < 4; ++i) {
                    int row = r0 + wv * 16 + hi * 4 + i;
                    if (row < N) {
                        if (lo == 0) s_src[row] = acc_s[i];
                        else if (lo == 1) s_dst[row] = acc_s[i];
                    }
                }
            }
        }
    }
}

// ---------------- combined CSR build: user nodes [0,NU), item nodes [NU,NU+NI) ----------------

__global__ __launch_bounds__(256) void hist_all(const int* __restrict__ ued, const int* __restrict__ ied,
                                                int EU, int EI, int NU, int* __restrict__ cnt)
{
    int e = blockIdx.x * blockDim.x + threadIdx.x;
    if (e >= EU + EI) return;
    int node = (e < EU) ? ued[EU + e] : NU + ied[EI + (e - EU)];
    atomicAdd(&cnt[node], 1);
}

__global__ __launch_bounds__(256) void scan_partial(const int* __restrict__ cnt, int N, int* __restrict__ aux)
{
    __shared__ int sm[4];
    int i = blockIdx.x * 256 + threadIdx.x;
    int v = (i < N) ? cnt[i] : 0;
#pragma unroll
    for (int o = 32; o > 0; o >>= 1) v += __shfl_down(v, o);
    if ((threadIdx.x & 63) == 0) sm[threadIdx.x >> 6] = v;
    __syncthreads();
    if (threadIdx.x == 0) aux[blockIdx.x] = sm[0] + sm[1] + sm[2] + sm[3];
}

__global__ __launch_bounds__(1024) void scan_aux(int* __restrict__ aux, int nb)
{
    __shared__ int s[1024];
    int t = threadIdx.x;
    int v = (t < nb) ? aux[t] : 0;
    s[t] = v;
    __syncthreads();
    for (int o = 1; o < 1024; o <<= 1) {
        int u = (t >= o) ? s[t - o] : 0;
        __syncthreads();
        s[t] += u;
        __syncthreads();
    }
    if (t < nb) aux[t] = t ? s[t - 1] : 0;
}

__global__ __launch_bounds__(256) void scan_write(const int* __restrict__ cnt, const int* __restrict__ aux,
                                                  int N, int* __restrict__ rowptr, int* __restrict__ cursor)
{
    __shared__ int s[256];
    int t = threadIdx.x;
    int i = blockIdx.x * 256 + t;
    int v = (i < N) ? cnt[i] : 0;
    s[t] = v;
    __syncthreads();
    for (int o = 1; o < 256; o <<= 1) {
        int u = (t >= o) ? s[t - o] : 0;
        __syncthreads();
        s[t] += u;
        __syncthreads();
    }
    int excl = aux[blockIdx.x] + s[t] - v;
    if (i < N) { rowptr[i] = excl; cursor[i] = excl; }
    if (i == N - 1) rowptr[N] = excl + v;
}

__global__ __launch_bounds__(256) void scatter_all(const int* __restrict__ ued, const int* __restrict__ ied,
                                                   const float* __restrict__ uval, const float* __restrict__ ival,
                                                   int EU, int EI, int NU, int* __restrict__ cursor,
                                                   int* __restrict__ srcs, float* __restrict__ evs)
{
    int e = blockIdx.x * blockDim.x + threadIdx.x;
    if (e >= EU + EI) return;
    int node, s; float val;
    if (e < EU) { node = ued[EU + e];            s = ued[e];      val = uval[e]; }
    else { int ee = e - EU; node = NU + ied[EI + ee]; s = ied[ee]; val = ival[ee]; }
    int p = atomicAdd(&cursor[node], 1);
    srcs[p] = s;
    evs[p] = val;
}

// ---------------- fused softmax + aggregation: 16 lanes per dst node ----------------
__global__ __launch_bounds__(256) void csr_agg16(const int* __restrict__ rowptr, const int* __restrict__ srcs,
                                                 const float* __restrict__ evs, const float* __restrict__ ssrc,
                                                 const float* __restrict__ sdst, const unsigned short* __restrict__ h,
                                                 float* __restrict__ out, int N)
{
    int n = (blockIdx.x * 256 + threadIdx.x) >> 4;   // one 16-lane group per node
    int l16 = threadIdx.x & 15;
    if (n >= N) return;
    int beg = rowptr[n], end = rowptr[n + 1];
    float sd = sdst[n];
    float m = -INFINITY, den = 0.f;
    float acc[8] = {0,0,0,0,0,0,0,0};
    for (int base = beg; base < end; base += 16) {
        int cnt = min(16, end - base);
        int sidx = 0; float l = -INFINITY, evv = 0.f;
        if (l16 < cnt) {
            sidx = srcs[base + l16];
            evv = evs[base + l16];
            float ll = ssrc[sidx] + sd;
            l = ll >= 0.f ? ll : 0.2f * ll;
        }
        float cm = l;
#pragma unroll
        for (int o = 8; o > 0; o >>= 1) cm = fmaxf(cm, __shfl_xor(cm, o, 16));
        float nm = fmaxf(m, cm);
        float sc = __expf(m - nm);       // first chunk: exp(-inf)=0, den/acc already 0
        den *= sc;
#pragma unroll
        for (int j = 0; j < 8; ++j) acc[j] *= sc;
        float p = (l16 < cnt) ? __expf(l - nm) * evv : 0.f;
        float ps = p;
#pragma unroll
        for (int o = 8; o > 0; o >>= 1) ps += __shfl_xor(ps, o, 16);
        den += ps;
        for (int k = 0; k < cnt; ++k) {
            float c = __shfl(p, k, 16);
            int s = __shfl(sidx, k, 16);
            const bf16x8 hv = *reinterpret_cast<const bf16x8*>(&h[(size_t)s * DIM + l16 * 8]);
#pragma unroll
            for (int j = 0; j < 8; ++j)
                acc[j] = fmaf(bf2f((unsigned short)hv[j]), c, acc[j]);
        }
        m = nm;
    }
    float inv = 1.f / (den + 1e-16f);
    float4 o0 = { acc[0]*inv, acc[1]*inv, acc[2]*inv, acc[3]*inv };
    float4 o1 = { acc[4]*inv, acc[5]*inv, acc[6]*inv, acc[7]*inv };
    float4* op = reinterpret_cast<float4*>(&out[(size_t)n * DIM + l16 * 8]);
    op[0] = o0;
    op[1] = o1;
}

// out = [elu(u[user_id]) ; elu(it[item_id])]
__global__ __launch_bounds__(256) void gather_out(const int* __restrict__ uid, const int* __restrict__ iid,
                                                  const float* __restrict__ u, const float* __restrict__ it,
                                                  float* __restrict__ out, int B)
{
    int t = blockIdx.x * blockDim.x + threadIdx.x;
    int total = B * DIM;
    if (t < total) {
        int b = t >> 7, j = t & 127;
        out[t] = elu_f(u[(size_t)uid[b] * DIM + j]);
    } else if (t < 2 * total) {
        int tt = t - total;
        int b = tt >> 7, j = tt & 127;
        out[t] = elu_f(it[(size_t)iid[b] * DIM + j]);
    }
}

extern "C" void kernel_launch(void* const* d_in, const int* in_sizes, int n_in,
                              void* d_out, int out_size, void* d_ws, size_t ws_size,
                              hipStream_t stream)
{
    const int*   uedg    = (const int*)d_in[0];
    const int*   iedg    = (const int*)d_in[1];
    const int*   user_id = (const int*)d_in[2];
    const int*   item_id = (const int*)d_in[3];
    const float* uval    = (const float*)d_in[4];
    const float* ival    = (const float*)d_in[5];
    const float* umat    = (const float*)d_in[6];
    const float* imat    = (const float*)d_in[7];
    const float* W_u1 = (const float*)d_in[8];
    const float* as_u1 = (const float*)d_in[9];
    const float* ad_u1 = (const float*)d_in[10];
    const float* W_u2 = (const float*)d_in[11];
    const float* as_u2 = (const float*)d_in[12];
    const float* ad_u2 = (const float*)d_in[13];
    const float* W_i1 = (const float*)d_in[14];
    const float* as_i1 = (const float*)d_in[15];
    const float* ad_i1 = (const float*)d_in[16];
    const float* W_i2 = (const float*)d_in[17];
    const float* as_i2 = (const float*)d_in[18];
    const float* ad_i2 = (const float*)d_in[19];

    const int EU = in_sizes[0] / 2;     // 400000
    const int EI = in_sizes[1] / 2;     // 200000
    const int B  = in_sizes[2];         // 4096
    const int NU = in_sizes[6] / DIM;   // 100000
    const int NI = in_sizes[7] / DIM;   // 50000
    const int NT = NU + NI;
    const int ET = EU + EI;

    unsigned short* h = (unsigned short*)d_ws;          // NU*DIM bf16
    float* xb_u   = (float*)(h + (size_t)NU * DIM);     // NU*DIM fp32
    float* xb_i   = xb_u + (size_t)NU * DIM;            // NI*DIM
    float* ssrc   = xb_i + (size_t)NI * DIM;            // NU
    float* sdst   = ssrc + NU;                          // NU
    int*   rp     = (int*)(sdst + NU);                  // NT+1
    int*   cursor = rp + (NT + 1);                      // NT
    int*   srcs   = cursor + NT;                        // ET
    float* evs    = (float*)(srcs + ET);                // ET
    int*   cnt    = (int*)(evs + ET);                   // NT
    int*   aux    = cnt + NT;                           // 1024
    unsigned short* Wt_a  = (unsigned short*)(aux + 1024);  // 4 layers x 128*128
    unsigned short* wa_a  = Wt_a + 4 * DIM * DIM;           // 4 layers x 2*128

    // ---- combined CSR build
    hipMemsetAsync(cnt, 0, (size_t)NT * 4, stream);
    hist_all<<<(ET + 255) / 256, 256, 0, stream>>>(uedg, iedg, EU, EI, NU, cnt);
    int nb = (NT + 255) / 256;
    scan_partial<<<nb, 256, 0, stream>>>(cnt, NT, aux);
    scan_aux<<<1, 1024, 0, stream>>>(aux, nb);
    scan_write<<<nb, 256, 0, stream>>>(cnt, aux, NT, rp, cursor);
    scatter_all<<<(ET + 255) / 256, 256, 0, stream>>>(uedg, iedg, uval, ival, EU, EI, NU, cursor, srcs, evs);

    // ---- per-layer W prep (order: u1, u2, i1, i2 in slots 0..3)
    const float* Ws[4]  = { W_u1, W_u2, W_i1, W_i2 };
    const float* asv[4] = { as_u1, as_u2, as_i1, as_i2 };
    const float* adv[4] = { ad_u1, ad_u2, ad_i1, ad_i2 };
    for (int i = 0; i < 4; ++i)
        prep_w<<<8, 256, 0, stream>>>(Ws[i], asv[i], adv[i], Wt_a + i * DIM * DIM, wa_a + i * 2 * DIM);

    auto layer = [&](const float* x, int slot, const int* rpl, float* outb, int N, bool applyElu) {
        int grid = (N + 63) / 64;
        const unsigned short* Wt = Wt_a + slot * DIM * DIM;
        const unsigned short* wa = wa_a + slot * 2 * DIM;
        if (applyElu)
            gemm_mfma<1><<<grid, 256, 0, stream>>>(x, Wt, wa, h, ssrc, sdst, N);
        else
            gemm_mfma<0><<<grid, 256, 0, stream>>>(x, Wt, wa, h, ssrc, sdst, N);
        csr_agg16<<<(N + 15) / 16, 256, 0, stream>>>(rpl, srcs, evs, ssrc, sdst, h, outb, N);
    };

    // Layer order mirrors the reference: i1, u1, i2, u2
    layer(imat, 2, rp + NU, xb_i, NI, false);
    layer(umat, 0, rp,      xb_u, NU, false);
    layer(xb_i, 3, rp + NU, xb_i, NI, true);
    layer(xb_u, 1, rp,      xb_u, NU, true);

    int total = 2 * B * DIM;
    gather_out<<<(total + 255) / 256, 256, 0, stream>>>(user_id, item_id, xb_u, xb_i, (float*)d_out, B);
}

// Round 6
// 217.995 us; speedup vs baseline: 13.3133x; 1.2519x over previous
//
#include <hip/hip_runtime.h>
#include <hip/hip_bf16.h>

#define DIM 128

typedef short bf16x8 __attribute__((ext_vector_type(8)));
typedef float f32x4  __attribute__((ext_vector_type(4)));

__device__ __forceinline__ float elu_f(float x) { return x > 0.f ? x : expm1f(x); }

__device__ __forceinline__ unsigned short f2bfu(float f) {
    return __builtin_bit_cast(unsigned short, __float2bfloat16(f));   // RNE
}
__device__ __forceinline__ float bf2f(unsigned short b) {
    return __uint_as_float(((unsigned)b) << 16);
}

// ---------------- per-layer W prep, all 4 layers in one launch ----------------
// grid: 32 blocks; layer = blockIdx.x>>3, blk = blockIdx.x&7 handles rows [16*blk,16*blk+16)
struct PrepArgs {
    const float* W[4];
    const float* as[4];
    const float* ad[4];
    unsigned short* Wt;   // 4 x DIM*DIM
    unsigned short* wa;   // 4 x 2*DIM
};

__global__ __launch_bounds__(256) void prep_w_all(PrepArgs p)
{
    __shared__ float as[DIM], ad[DIM];
    __shared__ float sr[4][2];
    const int layer = blockIdx.x >> 3;
    const int blk   = blockIdx.x & 7;
    const float* W  = p.W[layer];
    unsigned short* W_t = p.Wt + layer * DIM * DIM;
    unsigned short* wa  = p.wa + layer * 2 * DIM;
    const int t = threadIdx.x;
    if (t < DIM) as[t] = p.as[layer][t];
    else ad[t - DIM] = p.ad[layer][t - DIM];
    __syncthreads();
    const int half = t >> 7;            // row within pair
    const int c = t & 127;
    const int wv = t >> 6;
    const int k_end = blk * 16 + 16;
    for (int k0 = blk * 16; k0 < k_end; k0 += 2) {
        const int k = k0 + half;
        float w = W[k * DIM + c];
        W_t[c * DIM + k] = f2bfu(w);
        float vs = w * as[c], vd = w * ad[c];
#pragma unroll
        for (int o = 32; o > 0; o >>= 1) { vs += __shfl_down(vs, o); vd += __shfl_down(vd, o); }
        if ((t & 63) == 0) { sr[wv][0] = vs; sr[wv][1] = vd; }
        __syncthreads();
        if (t < 2) {
            const int kk = k0 + t;
            wa[kk]       = f2bfu(sr[2 * t][0] + sr[2 * t + 1][0]);
            wa[DIM + kk] = f2bfu(sr[2 * t][1] + sr[2 * t + 1][1]);
        }
        __syncthreads();
    }
}

// h(bf16) = elu?(x) @ W via bf16 MFMA; s_src/s_dst computed as extra MFMA columns (x @ wa).
// Block: 256 thr (4 waves). Tile: 64 rows x 128 cols. Wave w owns cols [32w,32w+32); wave w computes s for rows [16w,16w+16).
template<int APPLY_ELU>
__global__ __launch_bounds__(256) void gemm_mfma(const float* __restrict__ x, const unsigned short* __restrict__ W_t,
                                                 const unsigned short* __restrict__ wa,
                                                 unsigned short* __restrict__ h, float* __restrict__ s_src,
                                                 float* __restrict__ s_dst, int N)
{
    __shared__ short xs[64 * 128];          // 16 KB bf16 tile, XOR-swizzled rows
    const int t  = threadIdx.x;
    const int wv = t >> 6;
    const int l  = t & 63;
    const int lo = l & 15;
    const int hi = l >> 4;

    // ---- W fragments (bf16, pre-transposed): contiguous 16B loads
    bf16x8 wf[4][2];
#pragma unroll
    for (int cb2 = 0; cb2 < 2; ++cb2) {
        const unsigned short* base = W_t + (wv * 32 + cb2 * 16 + lo) * DIM + hi * 8;
#pragma unroll
        for (int kb = 0; kb < 4; ++kb)
            wf[kb][cb2] = *reinterpret_cast<const bf16x8*>(base + kb * 32);
    }
    // ---- s fragment: col 0 = wa_src, col 1 = wa_dst, cols 2-15 zero
    bf16x8 sfrag[4];
    if (lo < 2) {
        const unsigned short* sb = wa + lo * DIM + hi * 8;
#pragma unroll
        for (int kb = 0; kb < 4; ++kb)
            sfrag[kb] = *reinterpret_cast<const bf16x8*>(sb + kb * 32);
    } else {
#pragma unroll
        for (int kb = 0; kb < 4; ++kb) {
            bf16x8 z = { 0, 0, 0, 0, 0, 0, 0, 0 };
            sfrag[kb] = z;
        }
    }

    for (int r0 = blockIdx.x * 64; r0 < N; r0 += gridDim.x * 64) {
        __syncthreads();
        // ---- stage 64x128 fp32 -> bf16 LDS, swizzled: byte = row*256 + ((uc*16) ^ ((row&7)<<4))
#pragma unroll
        for (int i = 0; i < 4; ++i) {
            int unit = i * 256 + t;           // 1024 units of 8 bf16
            int row = unit >> 4, uc = unit & 15;
            int gr = r0 + row;
            float v[8] = {0,0,0,0,0,0,0,0};
            if (gr < N) {
                const float4* p = reinterpret_cast<const float4*>(&x[(size_t)gr * DIM + uc * 8]);
                float4 v0 = p[0], v1 = p[1];
                v[0]=v0.x; v[1]=v0.y; v[2]=v0.z; v[3]=v0.w;
                v[4]=v1.x; v[5]=v1.y; v[6]=v1.z; v[7]=v1.w;
                if (APPLY_ELU) {
#pragma unroll
                    for (int j = 0; j < 8; ++j) v[j] = elu_f(v[j]);
                }
            }
            bf16x8 bv;
#pragma unroll
            for (int j = 0; j < 8; ++j) bv[j] = (short)f2bfu(v[j]);
            int byte = row * 256 + ((uc * 16) ^ ((row & 7) << 4));
            *reinterpret_cast<bf16x8*>(reinterpret_cast<char*>(xs) + byte) = bv;
        }
        __syncthreads();

        // ---- compute: 4 row-blocks of 16
#pragma unroll
        for (int rb = 0; rb < 4; ++rb) {
            const int arow = rb * 16 + lo;    // A row this lane reads
            bf16x8 a[4];
#pragma unroll
            for (int kb = 0; kb < 4; ++kb) {
                int byte = arow * 256 + ((kb * 64 + hi * 16) ^ ((arow & 7) << 4));
                a[kb] = *reinterpret_cast<const bf16x8*>(reinterpret_cast<const char*>(xs) + byte);
            }
            f32x4 acc0 = {0.f,0.f,0.f,0.f}, acc1 = {0.f,0.f,0.f,0.f};
#pragma unroll
            for (int kb = 0; kb < 4; ++kb) {
                acc0 = __builtin_amdgcn_mfma_f32_16x16x32_bf16(a[kb], wf[kb][0], acc0, 0, 0, 0);
                acc1 = __builtin_amdgcn_mfma_f32_16x16x32_bf16(a[kb], wf[kb][1], acc1, 0, 0, 0);
            }
            // store h (bf16): lane holds rows rb*16 + hi*4 + i, cols wv*32 + lo and +16
#pragma unroll
            for (int i = 0; i < 4; ++i) {
                int row = r0 + rb * 16 + hi * 4 + i;
                if (row < N) {
                    h[(size_t)row * DIM + wv * 32 + lo]      = f2bfu(acc0[i]);
                    h[(size_t)row * DIM + wv * 32 + 16 + lo] = f2bfu(acc1[i]);
                }
            }
            // wave wv computes s for its own row-block via MFMA (cols 0,1 of x @ [wa_src|wa_dst|0..])
            if (rb == wv) {
                f32x4 acc_s = {0.f,0.f,0.f,0.f};
#pragma unroll
                for (int kb = 0; kb < 4; ++kb)
                    acc_s = __builtin_amdgcn_mfma_f32_16x16x32_bf16(a[kb], sfrag[kb], acc_s, 0, 0, 0);
#pragma unroll
                for (int i = 0; i < 4; ++i) {
                    int row = r0 + wv * 16 + hi * 4 + i;
                    if (row < N) {
                        if (lo == 0) s_src[row] = acc_s[i];
                        else if (lo == 1) s_dst[row] = acc_s[i];
                    }
                }
            }
        }
    }
}

// ---------------- combined CSR build: user nodes [0,NU), item nodes [NU,NU+NI) ----------------

// hist + rank: rank[e] = position of edge e within its dst segment; nodebuf[e] = combined node id
__global__ __launch_bounds__(256) void hist_all(const int* __restrict__ ued, const int* __restrict__ ied,
                                                int EU, int EI, int NU, int* __restrict__ cnt,
                                                int* __restrict__ rank, int* __restrict__ nodebuf)
{
    int e = blockIdx.x * blockDim.x + threadIdx.x;
    if (e >= EU + EI) return;
    int node = (e < EU) ? ued[EU + e] : NU + ied[EI + (e - EU)];
    nodebuf[e] = node;
    rank[e] = atomicAdd(&cnt[node], 1);
}

__global__ __launch_bounds__(256) void scan_partial(const int* __restrict__ cnt, int N, int* __restrict__ aux)
{
    __shared__ int sm[4];
    int i = blockIdx.x * 256 + threadIdx.x;
    int v = (i < N) ? cnt[i] : 0;
#pragma unroll
    for (int o = 32; o > 0; o >>= 1) v += __shfl_down(v, o);
    if ((threadIdx.x & 63) == 0) sm[threadIdx.x >> 6] = v;
    __syncthreads();
    if (threadIdx.x == 0) aux[blockIdx.x] = sm[0] + sm[1] + sm[2] + sm[3];
}

__global__ __launch_bounds__(1024) void scan_aux(int* __restrict__ aux, int nb)
{
    __shared__ int s[1024];
    int t = threadIdx.x;
    int v = (t < nb) ? aux[t] : 0;
    s[t] = v;
    __syncthreads();
    for (int o = 1; o < 1024; o <<= 1) {
        int u = (t >= o) ? s[t - o] : 0;
        __syncthreads();
        s[t] += u;
        __syncthreads();
    }
    if (t < nb) aux[t] = t ? s[t - 1] : 0;
}

__global__ __launch_bounds__(256) void scan_write(const int* __restrict__ cnt, const int* __restrict__ aux,
                                                  int N, int* __restrict__ rowptr)
{
    __shared__ int s[256];
    int t = threadIdx.x;
    int i = blockIdx.x * 256 + t;
    int v = (i < N) ? cnt[i] : 0;
    s[t] = v;
    __syncthreads();
    for (int o = 1; o < 256; o <<= 1) {
        int u = (t >= o) ? s[t - o] : 0;
        __syncthreads();
        s[t] += u;
        __syncthreads();
    }
    int excl = aux[blockIdx.x] + s[t] - v;
    if (i < N) rowptr[i] = excl;
    if (i == N - 1) rowptr[N] = excl + v;
}

// atomic-free scatter: p = rowptr[node] + rank[e]; single paired 8B store
__global__ __launch_bounds__(256) void scatter_all(const int* __restrict__ ued, const int* __restrict__ ied,
                                                   const float* __restrict__ uval, const float* __restrict__ ival,
                                                   int EU, int EI, const int* __restrict__ rowptr,
                                                   const int* __restrict__ rank, const int* __restrict__ nodebuf,
                                                   int2* __restrict__ epair)
{
    int e = blockIdx.x * blockDim.x + threadIdx.x;
    if (e >= EU + EI) return;
    int s; float val;
    if (e < EU) { s = ued[e]; val = uval[e]; }
    else { int ee = e - EU; s = ied[ee]; val = ival[ee]; }
    int node = nodebuf[e];
    int p = rowptr[node] + rank[e];
    epair[p] = make_int2(s, __float_as_int(val));
}

// ---------------- fused softmax + aggregation: 16 lanes per dst node ----------------
__global__ __launch_bounds__(256) void csr_agg16(const int* __restrict__ rowptr, const int2* __restrict__ epair,
                                                 const float* __restrict__ ssrc,
                                                 const float* __restrict__ sdst, const unsigned short* __restrict__ h,
                                                 float* __restrict__ out, int N)
{
    int n = (blockIdx.x * 256 + threadIdx.x) >> 4;   // one 16-lane group per node
    int l16 = threadIdx.x & 15;
    if (n >= N) return;
    int beg = rowptr[n], end = rowptr[n + 1];
    float sd = sdst[n];
    float m = -INFINITY, den = 0.f;
    float acc[8] = {0,0,0,0,0,0,0,0};
    for (int base = beg; base < end; base += 16) {
        int cnt = min(16, end - base);
        int sidx = 0; float l = -INFINITY, evv = 0.f;
        if (l16 < cnt) {
            int2 pr = epair[base + l16];
            sidx = pr.x;
            evv = __int_as_float(pr.y);
            float ll = ssrc[sidx] + sd;
            l = ll >= 0.f ? ll : 0.2f * ll;
        }
        float cm = l;
#pragma unroll
        for (int o = 8; o > 0; o >>= 1) cm = fmaxf(cm, __shfl_xor(cm, o, 16));
        float nm = fmaxf(m, cm);
        float sc = __expf(m - nm);       // first chunk: exp(-inf)=0, den/acc already 0
        den *= sc;
#pragma unroll
        for (int j = 0; j < 8; ++j) acc[j] *= sc;
        float p = (l16 < cnt) ? __expf(l - nm) * evv : 0.f;
        float ps = p;
#pragma unroll
        for (int o = 8; o > 0; o >>= 1) ps += __shfl_xor(ps, o, 16);
        den += ps;
        for (int k = 0; k < cnt; ++k) {
            float c = __shfl(p, k, 16);
            int s = __shfl(sidx, k, 16);
            const bf16x8 hv = *reinterpret_cast<const bf16x8*>(&h[(size_t)s * DIM + l16 * 8]);
#pragma unroll
            for (int j = 0; j < 8; ++j)
                acc[j] = fmaf(bf2f((unsigned short)hv[j]), c, acc[j]);
        }
        m = nm;
    }
    float inv = 1.f / (den + 1e-16f);
    float4 o0 = { acc[0]*inv, acc[1]*inv, acc[2]*inv, acc[3]*inv };
    float4 o1 = { acc[4]*inv, acc[5]*inv, acc[6]*inv, acc[7]*inv };
    float4* op = reinterpret_cast<float4*>(&out[(size_t)n * DIM + l16 * 8]);
    op[0] = o0;
    op[1] = o1;
}

// out = [elu(u[user_id]) ; elu(it[item_id])]
__global__ __launch_bounds__(256) void gather_out(const int* __restrict__ uid, const int* __restrict__ iid,
                                                  const float* __restrict__ u, const float* __restrict__ it,
                                                  float* __restrict__ out, int B)
{
    int t = blockIdx.x * blockDim.x + threadIdx.x;
    int total = B * DIM;
    if (t < total) {
        int b = t >> 7, j = t & 127;
        out[t] = elu_f(u[(size_t)uid[b] * DIM + j]);
    } else if (t < 2 * total) {
        int tt = t - total;
        int b = tt >> 7, j = tt & 127;
        out[t] = elu_f(it[(size_t)iid[b] * DIM + j]);
    }
}

extern "C" void kernel_launch(void* const* d_in, const int* in_sizes, int n_in,
                              void* d_out, int out_size, void* d_ws, size_t ws_size,
                              hipStream_t stream)
{
    const int*   uedg    = (const int*)d_in[0];
    const int*   iedg    = (const int*)d_in[1];
    const int*   user_id = (const int*)d_in[2];
    const int*   item_id = (const int*)d_in[3];
    const float* uval    = (const float*)d_in[4];
    const float* ival    = (const float*)d_in[5];
    const float* umat    = (const float*)d_in[6];
    const float* imat    = (const float*)d_in[7];
    const float* W_u1 = (const float*)d_in[8];
    const float* as_u1 = (const float*)d_in[9];
    const float* ad_u1 = (const float*)d_in[10];
    const float* W_u2 = (const float*)d_in[11];
    const float* as_u2 = (const float*)d_in[12];
    const float* ad_u2 = (const float*)d_in[13];
    const float* W_i1 = (const float*)d_in[14];
    const float* as_i1 = (const float*)d_in[15];
    const float* ad_i1 = (const float*)d_in[16];
    const float* W_i2 = (const float*)d_in[17];
    const float* as_i2 = (const float*)d_in[18];
    const float* ad_i2 = (const float*)d_in[19];

    const int EU = in_sizes[0] / 2;     // 400000
    const int EI = in_sizes[1] / 2;     // 200000
    const int B  = in_sizes[2];         // 4096
    const int NU = in_sizes[6] / DIM;   // 100000
    const int NI = in_sizes[7] / DIM;   // 50000
    const int NT = NU + NI;
    const int ET = EU + EI;

    // layout (all segment sizes 16B-multiples up through epair)
    unsigned short* h = (unsigned short*)d_ws;              // NU*DIM bf16
    unsigned short* Wt_a = h + (size_t)NU * DIM;            // 4*DIM*DIM
    unsigned short* wa_a = Wt_a + 4 * DIM * DIM;            // 4*2*DIM
    float* xb_u   = (float*)(wa_a + 4 * 2 * DIM);           // NU*DIM
    float* xb_i   = xb_u + (size_t)NU * DIM;                // NI*DIM
    float* ssrc   = xb_i + (size_t)NI * DIM;                // NU
    float* sdst   = ssrc + NU;                              // NU
    int2*  epair  = (int2*)(sdst + NU);                     // ET (8B each)
    int*   rank   = (int*)(epair + ET);                     // ET
    int*   nodebuf= rank + ET;                              // ET
    int*   cnt    = nodebuf + ET;                           // NT
    int*   rp     = cnt + NT;                               // NT+1
    int*   aux    = rp + (NT + 1);                          // 1024

    // ---- combined CSR build (rank trick: no atomic in scatter)
    hipMemsetAsync(cnt, 0, (size_t)NT * 4, stream);
    hist_all<<<(ET + 255) / 256, 256, 0, stream>>>(uedg, iedg, EU, EI, NU, cnt, rank, nodebuf);
    int nb = (NT + 255) / 256;
    scan_partial<<<nb, 256, 0, stream>>>(cnt, NT, aux);
    scan_aux<<<1, 1024, 0, stream>>>(aux, nb);
    scan_write<<<nb, 256, 0, stream>>>(cnt, aux, NT, rp);
    scatter_all<<<(ET + 255) / 256, 256, 0, stream>>>(uedg, iedg, uval, ival, EU, EI, rp, rank, nodebuf, epair);

    // ---- per-layer W prep (order: u1, u2, i1, i2 in slots 0..3), single launch
    PrepArgs pa;
    pa.W[0] = W_u1; pa.W[1] = W_u2; pa.W[2] = W_i1; pa.W[3] = W_i2;
    pa.as[0] = as_u1; pa.as[1] = as_u2; pa.as[2] = as_i1; pa.as[3] = as_i2;
    pa.ad[0] = ad_u1; pa.ad[1] = ad_u2; pa.ad[2] = ad_i1; pa.ad[3] = ad_i2;
    pa.Wt = Wt_a; pa.wa = wa_a;
    prep_w_all<<<32, 256, 0, stream>>>(pa);

    auto layer = [&](const float* x, int slot, const int* rpl, float* outb, int N, bool applyElu) {
        int grid = (N + 63) / 64;
        const unsigned short* Wt = Wt_a + slot * DIM * DIM;
        const unsigned short* wa = wa_a + slot * 2 * DIM;
        if (applyElu)
            gemm_mfma<1><<<grid, 256, 0, stream>>>(x, Wt, wa, h, ssrc, sdst, N);
        else
            gemm_mfma<0><<<grid, 256, 0, stream>>>(x, Wt, wa, h, ssrc, sdst, N);
        csr_agg16<<<(N + 15) / 16, 256, 0, stream>>>(rpl, epair, ssrc, sdst, h, outb, N);
    };

    // Layer order mirrors the reference: i1, u1, i2, u2
    layer(imat, 2, rp + NU, xb_i, NI, false);
    layer(umat, 0, rp,      xb_u, NU, false);
    layer(xb_i, 3, rp + NU, xb_i, NI, true);
    layer(xb_u, 1, rp,      xb_u, NU, true);

    int total = 2 * B * DIM;
    gather_out<<<(total + 255) / 256, 256, 0, stream>>>(user_id, item_id, xb_u, xb_i, (float*)d_out, B);
}

// Round 7
// 215.559 us; speedup vs baseline: 13.4637x; 1.0113x over previous
//
#include <hip/hip_runtime.h>
#include <hip/hip_bf16.h>

#define DIM 128

typedef short bf16x8 __attribute__((ext_vector_type(8)));
typedef float f32x4  __attribute__((ext_vector_type(4)));

__device__ __forceinline__ float elu_f(float x) { return x > 0.f ? x : expm1f(x); }

__device__ __forceinline__ unsigned short f2bfu(float f) {
    return __builtin_bit_cast(unsigned short, __float2bfloat16(f));   // RNE
}
__device__ __forceinline__ float bf2f(unsigned short b) {
    return __uint_as_float(((unsigned)b) << 16);
}

// ---------------- per-layer W prep, all 4 layers in one launch ----------------
struct PrepArgs {
    const float* W[4];
    const float* as[4];
    const float* ad[4];
    unsigned short* Wt;   // 4 x DIM*DIM
    unsigned short* wa;   // 4 x 2*DIM
};

__global__ __launch_bounds__(256) void prep_w_all(PrepArgs p)
{
    __shared__ float as[DIM], ad[DIM];
    __shared__ float sr[4][2];
    const int layer = blockIdx.x >> 3;
    const int blk   = blockIdx.x & 7;
    const float* W  = p.W[layer];
    unsigned short* W_t = p.Wt + layer * DIM * DIM;
    unsigned short* wa  = p.wa + layer * 2 * DIM;
    const int t = threadIdx.x;
    if (t < DIM) as[t] = p.as[layer][t];
    else ad[t - DIM] = p.ad[layer][t - DIM];
    __syncthreads();
    const int half = t >> 7;
    const int c = t & 127;
    const int wv = t >> 6;
    const int k_end = blk * 16 + 16;
    for (int k0 = blk * 16; k0 < k_end; k0 += 2) {
        const int k = k0 + half;
        float w = W[k * DIM + c];
        W_t[c * DIM + k] = f2bfu(w);
        float vs = w * as[c], vd = w * ad[c];
#pragma unroll
        for (int o = 32; o > 0; o >>= 1) { vs += __shfl_down(vs, o); vd += __shfl_down(vd, o); }
        if ((t & 63) == 0) { sr[wv][0] = vs; sr[wv][1] = vd; }
        __syncthreads();
        if (t < 2) {
            const int kk = k0 + t;
            wa[kk]       = f2bfu(sr[2 * t][0] + sr[2 * t + 1][0]);
            wa[DIM + kk] = f2bfu(sr[2 * t][1] + sr[2 * t + 1][1]);
        }
        __syncthreads();
    }
}

// h(bf16) = x @ W via bf16 MFMA; s_src/s_dst computed as extra MFMA columns (x @ wa).
// IN_BF16: x is bf16 (already elu'd by producer); else fp32.
template<int IN_BF16>
__global__ __launch_bounds__(256) void gemm_mfma(const float* __restrict__ xf, const unsigned short* __restrict__ xb,
                                                 const unsigned short* __restrict__ W_t,
                                                 const unsigned short* __restrict__ wa,
                                                 unsigned short* __restrict__ h, float* __restrict__ s_src,
                                                 float* __restrict__ s_dst, int N)
{
    __shared__ short xs[64 * 128];          // 16 KB bf16 tile, XOR-swizzled rows
    const int t  = threadIdx.x;
    const int wv = t >> 6;
    const int l  = t & 63;
    const int lo = l & 15;
    const int hi = l >> 4;

    bf16x8 wf[4][2];
#pragma unroll
    for (int cb2 = 0; cb2 < 2; ++cb2) {
        const unsigned short* base = W_t + (wv * 32 + cb2 * 16 + lo) * DIM + hi * 8;
#pragma unroll
        for (int kb = 0; kb < 4; ++kb)
            wf[kb][cb2] = *reinterpret_cast<const bf16x8*>(base + kb * 32);
    }
    bf16x8 sfrag[4];
    if (lo < 2) {
        const unsigned short* sb = wa + lo * DIM + hi * 8;
#pragma unroll
        for (int kb = 0; kb < 4; ++kb)
            sfrag[kb] = *reinterpret_cast<const bf16x8*>(sb + kb * 32);
    } else {
#pragma unroll
        for (int kb = 0; kb < 4; ++kb) {
            bf16x8 z = { 0, 0, 0, 0, 0, 0, 0, 0 };
            sfrag[kb] = z;
        }
    }

    for (int r0 = blockIdx.x * 64; r0 < N; r0 += gridDim.x * 64) {
        __syncthreads();
        // stage 64x128 -> bf16 LDS, swizzled: byte = row*256 + ((uc*16) ^ ((row&7)<<4))
#pragma unroll
        for (int i = 0; i < 4; ++i) {
            int unit = i * 256 + t;           // 1024 units of 8 bf16
            int row = unit >> 4, uc = unit & 15;
            int gr = r0 + row;
            bf16x8 bv = { 0, 0, 0, 0, 0, 0, 0, 0 };
            if (IN_BF16) {
                if (gr < N)
                    bv = *reinterpret_cast<const bf16x8*>(&xb[(size_t)gr * DIM + uc * 8]);
            } else {
                if (gr < N) {
                    const float4* p = reinterpret_cast<const float4*>(&xf[(size_t)gr * DIM + uc * 8]);
                    float4 v0 = p[0], v1 = p[1];
                    bv[0] = (short)f2bfu(v0.x); bv[1] = (short)f2bfu(v0.y);
                    bv[2] = (short)f2bfu(v0.z); bv[3] = (short)f2bfu(v0.w);
                    bv[4] = (short)f2bfu(v1.x); bv[5] = (short)f2bfu(v1.y);
                    bv[6] = (short)f2bfu(v1.z); bv[7] = (short)f2bfu(v1.w);
                }
            }
            int byte = row * 256 + ((uc * 16) ^ ((row & 7) << 4));
            *reinterpret_cast<bf16x8*>(reinterpret_cast<char*>(xs) + byte) = bv;
        }
        __syncthreads();

#pragma unroll
        for (int rb = 0; rb < 4; ++rb) {
            const int arow = rb * 16 + lo;
            bf16x8 a[4];
#pragma unroll
            for (int kb = 0; kb < 4; ++kb) {
                int byte = arow * 256 + ((kb * 64 + hi * 16) ^ ((arow & 7) << 4));
                a[kb] = *reinterpret_cast<const bf16x8*>(reinterpret_cast<const char*>(xs) + byte);
            }
            f32x4 acc0 = {0.f,0.f,0.f,0.f}, acc1 = {0.f,0.f,0.f,0.f};
#pragma unroll
            for (int kb = 0; kb < 4; ++kb) {
                acc0 = __builtin_amdgcn_mfma_f32_16x16x32_bf16(a[kb], wf[kb][0], acc0, 0, 0, 0);
                acc1 = __builtin_amdgcn_mfma_f32_16x16x32_bf16(a[kb], wf[kb][1], acc1, 0, 0, 0);
            }
#pragma unroll
            for (int i = 0; i < 4; ++i) {
                int row = r0 + rb * 16 + hi * 4 + i;
                if (row < N) {
                    h[(size_t)row * DIM + wv * 32 + lo]      = f2bfu(acc0[i]);
                    h[(size_t)row * DIM + wv * 32 + 16 + lo] = f2bfu(acc1[i]);
                }
            }
            if (rb == wv) {
                f32x4 acc_s = {0.f,0.f,0.f,0.f};
#pragma unroll
                for (int kb = 0; kb < 4; ++kb)
                    acc_s = __builtin_amdgcn_mfma_f32_16x16x32_bf16(a[kb], sfrag[kb], acc_s, 0, 0, 0);
#pragma unroll
                for (int i = 0; i < 4; ++i) {
                    int row = r0 + wv * 16 + hi * 4 + i;
                    if (row < N) {
                        if (lo == 0) s_src[row] = acc_s[i];
                        else if (lo == 1) s_dst[row] = acc_s[i];
                    }
                }
            }
        }
    }
}

// ---------------- combined CSR build: user nodes [0,NU), item nodes [NU,NU+NI) ----------------

__global__ __launch_bounds__(256) void zero_int(int* __restrict__ p, int n)
{
    int i = blockIdx.x * 256 + threadIdx.x;
    if (i < n) p[i] = 0;
}

__global__ __launch_bounds__(256) void hist_all(const int* __restrict__ ued, const int* __restrict__ ied,
                                                int EU, int EI, int NU, int* __restrict__ cnt,
                                                int* __restrict__ rank, int* __restrict__ nodebuf)
{
    int e = blockIdx.x * blockDim.x + threadIdx.x;
    if (e >= EU + EI) return;
    int node = (e < EU) ? ued[EU + e] : NU + ied[EI + (e - EU)];
    nodebuf[e] = node;
    rank[e] = atomicAdd(&cnt[node], 1);
}

__global__ __launch_bounds__(256) void scan_partial(const int* __restrict__ cnt, int N, int* __restrict__ aux)
{
    __shared__ int sm[4];
    int i = blockIdx.x * 256 + threadIdx.x;
    int v = (i < N) ? cnt[i] : 0;
#pragma unroll
    for (int o = 32; o > 0; o >>= 1) v += __shfl_down(v, o);
    if ((threadIdx.x & 63) == 0) sm[threadIdx.x >> 6] = v;
    __syncthreads();
    if (threadIdx.x == 0) aux[blockIdx.x] = sm[0] + sm[1] + sm[2] + sm[3];
}

__global__ __launch_bounds__(1024) void scan_aux(int* __restrict__ aux, int nb)
{
    __shared__ int s[1024];
    int t = threadIdx.x;
    int v = (t < nb) ? aux[t] : 0;
    s[t] = v;
    __syncthreads();
    for (int o = 1; o < 1024; o <<= 1) {
        int u = (t >= o) ? s[t - o] : 0;
        __syncthreads();
        s[t] += u;
        __syncthreads();
    }
    if (t < nb) aux[t] = t ? s[t - 1] : 0;
}

__global__ __launch_bounds__(256) void scan_write(const int* __restrict__ cnt, const int* __restrict__ aux,
                                                  int N, int* __restrict__ rowptr)
{
    __shared__ int s[256];
    int t = threadIdx.x;
    int i = blockIdx.x * 256 + t;
    int v = (i < N) ? cnt[i] : 0;
    s[t] = v;
    __syncthreads();
    for (int o = 1; o < 256; o <<= 1) {
        int u = (t >= o) ? s[t - o] : 0;
        __syncthreads();
        s[t] += u;
        __syncthreads();
    }
    int excl = aux[blockIdx.x] + s[t] - v;
    if (i < N) rowptr[i] = excl;
    if (i == N - 1) rowptr[N] = excl + v;
}

__global__ __launch_bounds__(256) void scatter_all(const int* __restrict__ ued, const int* __restrict__ ied,
                                                   const float* __restrict__ uval, const float* __restrict__ ival,
                                                   int EU, int EI, const int* __restrict__ rowptr,
                                                   const int* __restrict__ rank, const int* __restrict__ nodebuf,
                                                   int2* __restrict__ epair)
{
    int e = blockIdx.x * blockDim.x + threadIdx.x;
    if (e >= EU + EI) return;
    int s; float val;
    if (e < EU) { s = ued[e]; val = uval[e]; }
    else { int ee = e - EU; s = ied[ee]; val = ival[ee]; }
    int node = nodebuf[e];
    int p = rowptr[node] + rank[e];
    epair[p] = make_int2(s, __float_as_int(val));
}

// ---------------- fused softmax + aggregation: 16 lanes per dst node ----------------
// OUT_ELU_BF16: write bf16(elu(result)) (intermediate layer); else raw fp32 (final layer).
template<int OUT_ELU_BF16>
__global__ __launch_bounds__(256) void csr_agg16(const int* __restrict__ rowptr, const int2* __restrict__ epair,
                                                 const float* __restrict__ ssrc,
                                                 const float* __restrict__ sdst, const unsigned short* __restrict__ h,
                                                 void* __restrict__ outv, int N)
{
    int n = (blockIdx.x * 256 + threadIdx.x) >> 4;   // one 16-lane group per node
    int l16 = threadIdx.x & 15;
    if (n >= N) return;
    int beg = rowptr[n], end = rowptr[n + 1];
    float sd = sdst[n];
    float m = -INFINITY, den = 0.f;
    float acc[8] = {0,0,0,0,0,0,0,0};
    for (int base = beg; base < end; base += 16) {
        int cnt = min(16, end - base);
        int sidx = 0; float l = -INFINITY, evv = 0.f;
        if (l16 < cnt) {
            int2 pr = epair[base + l16];
            sidx = pr.x;
            evv = __int_as_float(pr.y);
            float ll = ssrc[sidx] + sd;
            l = ll >= 0.f ? ll : 0.2f * ll;
        }
        float cm = l;
#pragma unroll
        for (int o = 8; o > 0; o >>= 1) cm = fmaxf(cm, __shfl_xor(cm, o, 16));
        float nm = fmaxf(m, cm);
        float sc = __expf(m - nm);
        den *= sc;
#pragma unroll
        for (int j = 0; j < 8; ++j) acc[j] *= sc;
        float p = (l16 < cnt) ? __expf(l - nm) * evv : 0.f;
        float ps = p;
#pragma unroll
        for (int o = 8; o > 0; o >>= 1) ps += __shfl_xor(ps, o, 16);
        den += ps;
        // batched aggregation: issue 4 independent gathers, then FMA
        for (int k0 = 0; k0 < cnt; k0 += 4) {
            bf16x8 hv[4]; float cc[4];
#pragma unroll
            for (int j = 0; j < 4; ++j) {
                int k = k0 + j;
                cc[j] = 0.f;
                if (k < cnt) {
                    cc[j] = __shfl(p, k, 16);
                    int s = __shfl(sidx, k, 16);
                    hv[j] = *reinterpret_cast<const bf16x8*>(&h[(size_t)s * DIM + l16 * 8]);
                }
            }
#pragma unroll
            for (int j = 0; j < 4; ++j) {
                if (k0 + j < cnt) {
#pragma unroll
                    for (int q = 0; q < 8; ++q)
                        acc[q] = fmaf(bf2f((unsigned short)hv[j][q]), cc[j], acc[q]);
                }
            }
        }
        m = nm;
    }
    float inv = 1.f / (den + 1e-16f);
    if (OUT_ELU_BF16) {
        unsigned short* ob = (unsigned short*)outv;
        bf16x8 o;
#pragma unroll
        for (int q = 0; q < 8; ++q) o[q] = (short)f2bfu(elu_f(acc[q] * inv));
        *reinterpret_cast<bf16x8*>(&ob[(size_t)n * DIM + l16 * 8]) = o;
    } else {
        float* of = (float*)outv;
        float4 o0 = { acc[0]*inv, acc[1]*inv, acc[2]*inv, acc[3]*inv };
        float4 o1 = { acc[4]*inv, acc[5]*inv, acc[6]*inv, acc[7]*inv };
        float4* op = reinterpret_cast<float4*>(&of[(size_t)n * DIM + l16 * 8]);
        op[0] = o0;
        op[1] = o1;
    }
}

// out = [elu(u[user_id]) ; elu(it[item_id])]
__global__ __launch_bounds__(256) void gather_out(const int* __restrict__ uid, const int* __restrict__ iid,
                                                  const float* __restrict__ u, const float* __restrict__ it,
                                                  float* __restrict__ out, int B)
{
    int t = blockIdx.x * blockDim.x + threadIdx.x;
    int total = B * DIM;
    if (t < total) {
        int b = t >> 7, j = t & 127;
        out[t] = elu_f(u[(size_t)uid[b] * DIM + j]);
    } else if (t < 2 * total) {
        int tt = t - total;
        int b = tt >> 7, j = tt & 127;
        out[t] = elu_f(it[(size_t)iid[b] * DIM + j]);
    }
}

extern "C" void kernel_launch(void* const* d_in, const int* in_sizes, int n_in,
                              void* d_out, int out_size, void* d_ws, size_t ws_size,
                              hipStream_t stream)
{
    const int*   uedg    = (const int*)d_in[0];
    const int*   iedg    = (const int*)d_in[1];
    const int*   user_id = (const int*)d_in[2];
    const int*   item_id = (const int*)d_in[3];
    const float* uval    = (const float*)d_in[4];
    const float* ival    = (const float*)d_in[5];
    const float* umat    = (const float*)d_in[6];
    const float* imat    = (const float*)d_in[7];
    const float* W_u1 = (const float*)d_in[8];
    const float* as_u1 = (const float*)d_in[9];
    const float* ad_u1 = (const float*)d_in[10];
    const float* W_u2 = (const float*)d_in[11];
    const float* as_u2 = (const float*)d_in[12];
    const float* ad_u2 = (const float*)d_in[13];
    const float* W_i1 = (const float*)d_in[14];
    const float* as_i1 = (const float*)d_in[15];
    const float* ad_i1 = (const float*)d_in[16];
    const float* W_i2 = (const float*)d_in[17];
    const float* as_i2 = (const float*)d_in[18];
    const float* ad_i2 = (const float*)d_in[19];

    const int EU = in_sizes[0] / 2;     // 400000
    const int EI = in_sizes[1] / 2;     // 200000
    const int B  = in_sizes[2];         // 4096
    const int NU = in_sizes[6] / DIM;   // 100000
    const int NI = in_sizes[7] / DIM;   // 50000
    const int NT = NU + NI;
    const int ET = EU + EI;

    unsigned short* h    = (unsigned short*)d_ws;           // NU*DIM bf16
    unsigned short* Wt_a = h + (size_t)NU * DIM;            // 4*DIM*DIM
    unsigned short* wa_a = Wt_a + 4 * DIM * DIM;            // 4*2*DIM
    unsigned short* xbb_u= wa_a + 4 * 2 * DIM;              // NU*DIM bf16 (elu'd intermediates)
    unsigned short* xbb_i= xbb_u + (size_t)NU * DIM;        // NI*DIM bf16
    float* xbf_u  = (float*)(xbb_i + (size_t)NI * DIM);     // NU*DIM fp32 (final)
    float* xbf_i  = xbf_u + (size_t)NU * DIM;               // NI*DIM fp32
    float* ssrc   = xbf_i + (size_t)NI * DIM;               // NU
    float* sdst   = ssrc + NU;                              // NU
    int2*  epair  = (int2*)(sdst + NU);                     // ET
    int*   rank   = (int*)(epair + ET);                     // ET
    int*   nodebuf= rank + ET;                              // ET
    int*   cnt    = nodebuf + ET;                           // NT
    int*   rp     = cnt + NT;                               // NT+1
    int*   aux    = rp + (NT + 1);                          // 1024

    // ---- combined CSR build (rank trick: no atomic in scatter)
    zero_int<<<(NT + 255) / 256, 256, 0, stream>>>(cnt, NT);
    hist_all<<<(ET + 255) / 256, 256, 0, stream>>>(uedg, iedg, EU, EI, NU, cnt, rank, nodebuf);
    int nb = (NT + 255) / 256;
    scan_partial<<<nb, 256, 0, stream>>>(cnt, NT, aux);
    scan_aux<<<1, 1024, 0, stream>>>(aux, nb);
    scan_write<<<nb, 256, 0, stream>>>(cnt, aux, NT, rp);
    scatter_all<<<(ET + 255) / 256, 256, 0, stream>>>(uedg, iedg, uval, ival, EU, EI, rp, rank, nodebuf, epair);

    // ---- per-layer W prep (slots: 0=u1, 1=u2, 2=i1, 3=i2)
    PrepArgs pa;
    pa.W[0] = W_u1; pa.W[1] = W_u2; pa.W[2] = W_i1; pa.W[3] = W_i2;
    pa.as[0] = as_u1; pa.as[1] = as_u2; pa.as[2] = as_i1; pa.as[3] = as_i2;
    pa.ad[0] = ad_u1; pa.ad[1] = ad_u2; pa.ad[2] = ad_i1; pa.ad[3] = ad_i2;
    pa.Wt = Wt_a; pa.wa = wa_a;
    prep_w_all<<<32, 256, 0, stream>>>(pa);

    // ---- layers (reference order: i1, u1, i2, u2)
    // i1: fp32 in (imat) -> agg writes bf16+elu to xbb_i
    {
        int grid = (NI + 63) / 64;
        gemm_mfma<0><<<grid, 256, 0, stream>>>(imat, nullptr, Wt_a + 2 * DIM * DIM, wa_a + 2 * 2 * DIM, h, ssrc, sdst, NI);
        csr_agg16<1><<<(NI + 15) / 16, 256, 0, stream>>>(rp + NU, epair, ssrc, sdst, h, xbb_i, NI);
    }
    // u1: fp32 in (umat) -> bf16+elu to xbb_u
    {
        int grid = (NU + 63) / 64;
        gemm_mfma<0><<<grid, 256, 0, stream>>>(umat, nullptr, Wt_a + 0 * DIM * DIM, wa_a + 0 * 2 * DIM, h, ssrc, sdst, NU);
        csr_agg16<1><<<(NU + 15) / 16, 256, 0, stream>>>(rp, epair, ssrc, sdst, h, xbb_u, NU);
    }
    // i2: bf16 in (xbb_i) -> fp32 raw to xbf_i
    {
        int grid = (NI + 63) / 64;
        gemm_mfma<1><<<grid, 256, 0, stream>>>(nullptr, xbb_i, Wt_a + 3 * DIM * DIM, wa_a + 3 * 2 * DIM, h, ssrc, sdst, NI);
        csr_agg16<0><<<(NI + 15) / 16, 256, 0, stream>>>(rp + NU, epair, ssrc, sdst, h, xbf_i, NI);
    }
    // u2: bf16 in (xbb_u) -> fp32 raw to xbf_u
    {
        int grid = (NU + 63) / 64;
        gemm_mfma<1><<<grid, 256, 0, stream>>>(nullptr, xbb_u, Wt_a + 1 * DIM * DIM, wa_a + 1 * 2 * DIM, h, ssrc, sdst, NU);
        csr_agg16<0><<<(NU + 15) / 16, 256, 0, stream>>>(rp, epair, ssrc, sdst, h, xbf_u, NU);
    }

    int total = 2 * B * DIM;
    gather_out<<<(total + 255) / 256, 256, 0, stream>>>(user_id, item_id, xbf_u, xbf_i, (float*)d_out, B);
}